// Round 13
// baseline (467.331 us; speedup 1.0000x reference)
//
#include <hip/hip_runtime.h>
#include <cmath>

// ---------------------------------------------------------------------------
// RPN head post-processing (mmdet GetBboxes-style), exact-semantics HIP port.
//
// Correctness: ordering-critical math fp64-exact (sigmoid, delta2bbox) or
// fp64-equivalent (IoU: fp32 filter + fp64 fallback band); top-k ordering on
// raw fp32 logit bits (monotone == fp64 sigmoid order; ties -> lower index).
//
// R12 PM: k_hist's 467k random-address global atomics produced 14 MB of
// fine-grained RMW traffic (WRITE_SIZE counter) -- atomic-throughput bound
// at 65us. R13: 12-bit buckets (4096 bins = 16KB LDS) -> per-block PRIVATE
// LDS histogram + plain coalesced store; k_find reduces private hists.
// Zero global atomics. Coarser tie-bucket (~1400 els est, 8192 cap) =>
// k_fill cand-rank reshaped to the k_rank LDS-tile pattern (exact).
// ---------------------------------------------------------------------------

#define NPRE 2000
#define NPOST 1000

static __device__ __forceinline__ unsigned int flipf_dev(float f) {
  unsigned int u = __float_as_uint(f);
  return (u & 0x80000000u) ? ~u : (u | 0x80000000u);
}
static __device__ __forceinline__ float unflipf_dev(unsigned int k) {
  unsigned int u = (k & 0x80000000u) ? (k ^ 0x80000000u) : ~k;
  return __uint_as_float(u);
}
static __device__ __forceinline__ unsigned long long flip64_dev(double d) {
  unsigned long long u = (unsigned long long)__double_as_longlong(d);
  return (u & 0x8000000000000000ull) ? ~u : (u | 0x8000000000000000ull);
}

struct RPNParams {
  const float* cls[5];
  const float* bbox[5];
  const float* anc[5];
  unsigned int* hist;          // [70][4096] private per-block 12-bit hists
  unsigned int* mainCount;     // [10]
  unsigned int* candCount;     // [10]
  unsigned int* Bstar;         // [10]
  unsigned long long* mainEK;  // [10][2048]  packed (key<<32)|~idx
  unsigned long long* candEK;  // [10][8192]
  unsigned long long* ekG;     // [10][2048]  assembled top-2000 (+pads)
  unsigned int* partialR;      // [10][8][2048] sliced ranks
  double* selBoxes;            // [10][2000][4]
  double* selScores;           // [10][2000]
  unsigned long long* mask;    // [10][2000][32]
  double* postScores;          // [10][1000]
  float* postBoxes;            // [10][1000][4]
  unsigned int* partial;       // [2][20][5000]
  float* out;                  // [2][1000][4]
};

__device__ __constant__ int c_NL[5]  = {201600, 50400, 12600, 3150, 819};
__device__ __constant__ int c_HW[5]  = {67200, 16800, 4200, 1050, 273};
// blocks-per-task at 2048 elements/block (levels 0..3 x 2 images) -- compact
__device__ __constant__ int c_BPT[8] = {99, 99, 25, 25, 7, 7, 2, 2};
// blocks-per-task at 8192 elements/block -- hist (total 70)
__device__ __constant__ int c_BPT12[8] = {25, 25, 7, 7, 2, 2, 1, 1};

static __device__ __forceinline__ void map_block(int bx, int& t, int& chunk) {
  int start = 0;
  t = 0;
  for (int k = 0; k < 8; k++) {
    if (bx < start + c_BPT[k]) { t = k; break; }
    start += c_BPT[k];
  }
  chunk = bx - start;
}
static __device__ __forceinline__ void map_block12(int bx, int& t, int& chunk) {
  int start = 0;
  t = 0;
  for (int k = 0; k < 8; k++) {
    if (bx < start + c_BPT12[k]) { t = k; break; }
    start += c_BPT12[k];
  }
  chunk = bx - start;
}

// --- 1. per-block PRIVATE 12-bit histogram (LDS atomics, no global atomics) -
__global__ __launch_bounds__(1024) void k_hist(RPNParams p) {
  __shared__ unsigned int lh[4096];
  int t, chunk;
  map_block12(blockIdx.x, t, chunk);
  int l = t >> 1, b = t & 1;
  int N = c_NL[l], HW = c_HW[l];
  const float* cls = p.cls[l] + (size_t)b * 3 * HW;
  int tid = threadIdx.x;
  for (int i = tid; i < 4096; i += 1024) lh[i] = 0;
  __syncthreads();
  int base = chunk * 8192 + tid;
#pragma unroll
  for (int k = 0; k < 8; k++) {
    int n = base + k * 1024;
    if (n < N) {
      int a = n % 3, hw = n / 3;
      unsigned int key = flipf_dev(cls[a * HW + hw]);
      atomicAdd(&lh[key >> 20], 1u);
    }
  }
  __syncthreads();
  unsigned int* hout = p.hist + (size_t)blockIdx.x * 4096;
  for (int i = tid; i < 4096; i += 1024) hout[i] = lh[i];
}

// --- 2. reduce private hists + find threshold bucket B* (12-bit) ------------
__global__ void k_find(RPNParams p) {
  int t = blockIdx.x;  // 0..7
  __shared__ unsigned int H[4096];
  __shared__ unsigned int S[1024];
  __shared__ int gsel;
  __shared__ unsigned int baseAbove;
  int tid = threadIdx.x;  // 1024
  int start = 0;
  for (int k = 0; k < t; k++) start += c_BPT12[k];
  int bpt = c_BPT12[t];
  for (int bin = tid; bin < 4096; bin += 1024) {
    unsigned int s = 0;
    for (int bb = 0; bb < bpt; bb++)
      s += p.hist[(size_t)(start + bb) * 4096 + bin];
    H[bin] = s;
  }
  __syncthreads();
  S[tid] = H[tid * 4] + H[tid * 4 + 1] + H[tid * 4 + 2] + H[tid * 4 + 3];
  __syncthreads();
  for (int off = 1; off < 1024; off <<= 1) {
    unsigned int add = (tid + off < 1024) ? S[tid + off] : 0u;
    __syncthreads();
    S[tid] += add;
    __syncthreads();
  }
  const unsigned int need = NPRE;
  if (S[tid] >= need && (tid == 1023 || S[tid + 1] < need)) {
    gsel = tid;
    baseAbove = (tid == 1023) ? 0u : S[tid + 1];
  }
  __syncthreads();
  if (tid == 0) {
    int gg = gsel;
    unsigned int c = baseAbove;
    int bstar = gg * 4;
    for (int bb = 3; bb >= 0; bb--) {
      c += H[gg * 4 + bb];
      if (c >= need) { bstar = gg * 4 + bb; break; }
    }
    p.Bstar[t] = (unsigned int)bstar;
  }
}

// --- 3. compaction: above-bucket -> main, == bucket -> cand (12-bit) --------
__global__ void k_compact(RPNParams p) {
  int t, chunk;
  map_block(blockIdx.x, t, chunk);
  int l = t >> 1, b = t & 1;
  int N = c_NL[l], HW = c_HW[l];
  const float* cls = p.cls[l] + (size_t)b * 3 * HW;
  unsigned int Bs = p.Bstar[t];
  int base = chunk * 2048 + threadIdx.x;
  for (int k = 0; k < 2; k++) {
    int n = base + k * 1024;
    if (n < N) {
      int a = n % 3, hw = n / 3;
      unsigned int key = flipf_dev(cls[a * HW + hw]);
      unsigned int hi = key >> 20;
      unsigned long long ek =
          ((unsigned long long)key << 32) | (unsigned int)(~(unsigned int)n);
      if (hi > Bs) {
        unsigned int pos = atomicAdd(&p.mainCount[t], 1u);
        if (pos < 2048u) p.mainEK[(size_t)t * 2048 + pos] = ek;
      } else if (hi == Bs) {
        unsigned int pos = atomicAdd(&p.candCount[t], 1u);
        if (pos < 8192u) p.candEK[(size_t)t * 8192 + pos] = ek;
      }
    }
  }
}

// --- 4a. fill ekG[t][2048]: exact top-2000 keys + pads ----------------------
// cand ranking in the k_rank LDS-tile pattern (nC can be ~1400 at 12-bit).
__global__ void k_fill(RPNParams p) {
  int t = blockIdx.x;  // 0..9
  int l = t >> 1, b = t & 1;
  int N = c_NL[l], HW = c_HW[l];
  int tid = threadIdx.x;  // 256
  unsigned long long* ekG = p.ekG + (size_t)t * 2048;
  if (N >= NPRE) {
    unsigned int cGT = min(p.mainCount[t], 2000u);
    unsigned int nC = min(p.candCount[t], 8192u);
    unsigned int needIn = 2000u - cGT;
    for (unsigned int m = tid; m < cGT; m += 256)
      ekG[m] = p.mainEK[(size_t)t * 2048 + m];
    const unsigned long long* cek = p.candEK + (size_t)t * 8192;
    __shared__ unsigned long long sl[256];
    for (unsigned int estrip = 0; estrip < nC; estrip += 2048) {
      unsigned long long ve[8];
      unsigned int r[8];
      bool en[8];
#pragma unroll
      for (int k = 0; k < 8; k++) {
        unsigned int e = estrip + k * 256 + tid;
        en[k] = e < nC;
        ve[k] = en[k] ? cek[e] : 0ull;
        r[k] = 0;
      }
      for (unsigned int jb = 0; jb < nC; jb += 256) {
        __syncthreads();
        sl[tid] = (jb + tid < nC) ? cek[jb + tid] : 0ull;
        __syncthreads();
        int lim = (int)min(256u, nC - jb);
        for (int j = 0; j < lim; j++) {
          unsigned long long vj = sl[j];
#pragma unroll
          for (int k = 0; k < 8; k++) r[k] += (vj > ve[k]) ? 1u : 0u;
        }
      }
#pragma unroll
      for (int k = 0; k < 8; k++)
        if (en[k] && r[k] < needIn) ekG[cGT + r[k]] = ve[k];
    }
    for (unsigned int r2 = 2000u + tid; r2 < 2048u; r2 += 256)
      ekG[r2] = (unsigned long long)(unsigned int)(~r2);
  } else {
    // level 4 (N=819): pad path -- key 0 pads below all finite logits
    const float* cls = p.cls[l] + (size_t)b * 3 * HW;
    for (int r = tid; r < 2048; r += 256) {
      if (r < N) {
        int a = r % 3, hw = r / 3;
        unsigned int key = flipf_dev(cls[a * HW + hw]);
        ekG[r] = ((unsigned long long)key << 32) |
                 (unsigned int)(~(unsigned int)r);
      } else {
        ekG[r] = (unsigned long long)(unsigned int)(~(unsigned int)r);
      }
    }
  }
}

// --- 4b. sliced counting-rank: 8 slices x 10 tasks --------------------------
__global__ void k_rank(RPNParams p) {
  int t = blockIdx.x >> 3;
  int s = blockIdx.x & 7;
  int tid = threadIdx.x;  // 256
  __shared__ unsigned long long sl[256];
  const unsigned long long* ekG = p.ekG + (size_t)t * 2048;
  sl[tid] = ekG[s * 256 + tid];
  __syncthreads();
  unsigned long long ve[8];
  unsigned int r[8];
#pragma unroll
  for (int k = 0; k < 8; k++) {
    ve[k] = ekG[k * 256 + tid];
    r[k] = 0;
  }
  for (int j = 0; j < 256; j++) {
    unsigned long long vj = sl[j];
#pragma unroll
    for (int k = 0; k < 8; k++) r[k] += (vj > ve[k]) ? 1u : 0u;
  }
  unsigned int* out = p.partialR + ((size_t)t * 8 + s) * 2048;
#pragma unroll
  for (int k = 0; k < 8; k++) out[k * 256 + tid] = r[k];
}

// --- 4c. scatter by total rank + fp64 decode --------------------------------
__global__ void k_scatter(RPNParams p) {
  int t = blockIdx.x;  // 0..9
  int l = t >> 1, b = t & 1;
  int HW = c_HW[l];
  int tid = threadIdx.x;  // 1024
  __shared__ unsigned long long srt[2048];
  const unsigned long long* ekG = p.ekG + (size_t)t * 2048;
  for (int e = tid; e < 2048; e += 1024) {
    unsigned int rk = 0;
#pragma unroll
    for (int s = 0; s < 8; s++)
      rk += p.partialR[((size_t)t * 8 + s) * 2048 + e];
    srt[rk] = ekG[e];
  }
  __syncthreads();

  const double RCLIP = fabs(log(16.0 / 1000.0));  // mmdet wh_ratio_clip
  const float* bbx = p.bbox[l] + (size_t)b * 12 * HW;
  const float* anc = p.anc[l];
  for (int r = tid; r < NPRE; r += 1024) {
    unsigned long long v = srt[r];
    unsigned int key = (unsigned int)(v >> 32);
    double* SB = p.selBoxes + ((size_t)t * NPRE + r) * 4;
    if (key == 0u) {  // pad: zero anchors/deltas -> zero box, score -1
      SB[0] = 0.0; SB[1] = 0.0; SB[2] = 0.0; SB[3] = 0.0;
      p.selScores[(size_t)t * NPRE + r] = -1.0;
    } else {
      unsigned int idx = ~(unsigned int)(v & 0xFFFFFFFFull);
      int a = (int)(idx % 3u);
      int hw = (int)(idx / 3u);
      double d0 = (double)bbx[(a * 4 + 0) * HW + hw];
      double d1 = (double)bbx[(a * 4 + 1) * HW + hw];
      double d2 = (double)bbx[(a * 4 + 2) * HW + hw];
      double d3 = (double)bbx[(a * 4 + 3) * HW + hw];
      double a0 = (double)anc[(size_t)idx * 4 + 0];
      double a1 = (double)anc[(size_t)idx * 4 + 1];
      double a2 = (double)anc[(size_t)idx * 4 + 2];
      double a3 = (double)anc[(size_t)idx * 4 + 3];
      double dw = fmin(fmax(d2, -RCLIP), RCLIP);
      double dh = fmin(fmax(d3, -RCLIP), RCLIP);
      double pw = a2 - a0, ph = a3 - a1;
      double px = (a0 + a2) * 0.5, py = (a1 + a3) * 0.5;
      double gw = pw * exp(dw), gh = ph * exp(dh);
      double gx = px + pw * d0, gy = py + ph * d1;
      double x1 = fmin(fmax(gx - 0.5 * gw, 0.0), 1344.0);
      double y1 = fmin(fmax(gy - 0.5 * gh, 0.0), 800.0);
      double x2 = fmin(fmax(gx + 0.5 * gw, 0.0), 1344.0);
      double y2 = fmin(fmax(gy + 0.5 * gh, 0.0), 800.0);
      SB[0] = x1; SB[1] = y1; SB[2] = x2; SB[3] = y2;
      float f = unflipf_dev(key);
      p.selScores[(size_t)t * NPRE + r] = 1.0 / (1.0 + exp(-(double)f));
    }
  }
}

// --- 5. IoU -> suppression bitmask. 8 rows share each column load. ----------
__global__ __launch_bounds__(640) void k_iou(RPNParams p) {
  int bx = blockIdx.x;
  int t = bx / 25;
  int q = bx % 25;
  __shared__ float X1[2048], Y1[2048], X2[2048], Y2[2048], AR[2048];
  const double* SB = p.selBoxes + (size_t)t * NPRE * 4;
  for (int i = threadIdx.x; i < 2048; i += 640) {
    float x1 = 0.f, y1 = 0.f, x2 = 0.f, y2 = 0.f;
    if (i < NPRE) {
      x1 = (float)SB[i * 4 + 0]; y1 = (float)SB[i * 4 + 1];
      x2 = (float)SB[i * 4 + 2]; y2 = (float)SB[i * 4 + 3];
    }
    X1[i] = x1; Y1[i] = y1; X2[i] = x2; Y2[i] = y2;
    AR[i] = (x2 - x1) * (y2 - y1);
  }
  __syncthreads();
  int wave = threadIdx.x >> 6, lane = threadIdx.x & 63;
  int g = q + 25 * wave;  // [0,250)
  int i0 = g * 8;
  float x1i[8], y1i[8], x2i[8], y2i[8], ai[8];
#pragma unroll
  for (int r = 0; r < 8; r++) {
    int i = i0 + r;
    x1i[r] = X1[i]; y1i[r] = Y1[i]; x2i[r] = X2[i]; y2i[r] = Y2[i];
    ai[r] = AR[i];
  }
  int c0 = i0 >> 6;
  int j0 = c0 * 64 + lane;
  float cx1 = X1[j0], cy1 = Y1[j0], cx2 = X2[j0], cy2 = Y2[j0], car = AR[j0];
  for (int k = c0; k < 32; k++) {
    float nx1 = 0.f, ny1 = 0.f, nx2 = 0.f, ny2 = 0.f, nar = 0.f;
    if (k + 1 < 32) {  // prefetch next column word
      int jn = (k + 1) * 64 + lane;
      nx1 = X1[jn]; ny1 = Y1[jn]; nx2 = X2[jn]; ny2 = Y2[jn];
      nar = AR[jn];
    }
    int j = k * 64 + lane;
    bool jin = j < NPRE;
    bool pred[8], need[8];
    bool needAny = false;
#pragma unroll
    for (int r = 0; r < 8; r++) {
      int i = i0 + r;
      bool valid = jin && (j > i);
      float lx = fmaxf(x1i[r], cx1), ly = fmaxf(y1i[r], cy1);
      float rx = fminf(x2i[r], cx2), ry = fminf(y2i[r], cy2);
      float w = fmaxf(rx - lx, 0.0f), h = fmaxf(ry - ly, 0.0f);
      float inter = w * h;
      float uni = fmaxf(ai[r] + car - inter, 1e-6f);
      float diff = inter - 0.7f * uni;
      pred[r] = valid && (diff > 0.0f);
      need[r] = valid && (fabsf(diff) <= 4.0f + 1e-5f * uni);
      needAny |= need[r];
    }
    if (__any(needAny)) {  // rare: exact fp64 near the 0.7 boundary
#pragma unroll
      for (int r = 0; r < 8; r++) {
        if (need[r]) {
          int i = i0 + r;
          double a0 = SB[i * 4 + 0], b0 = SB[i * 4 + 1];
          double a2 = SB[i * 4 + 2], b2 = SB[i * 4 + 3];
          double c0d = SB[j * 4 + 0], d0 = SB[j * 4 + 1];
          double c2 = SB[j * 4 + 2], d2 = SB[j * 4 + 3];
          double dai = (a2 - a0) * (b2 - b0);
          double daj = (c2 - c0d) * (d2 - d0);
          double lxd = fmax(a0, c0d), lyd = fmax(b0, d0);
          double rxd = fmin(a2, c2), ryd = fmin(b2, d2);
          double wd = fmax(rxd - lxd, 0.0), hd = fmax(ryd - lyd, 0.0);
          double interd = wd * hd;
          double unid = fmax(dai + daj - interd, 1e-6);
          pred[r] = (interd / unid) > 0.7;
        }
      }
    }
#pragma unroll
    for (int r = 0; r < 8; r++) {
      unsigned long long word = __ballot(pred[r]);
      if (lane == 0) p.mask[((size_t)t * NPRE + i0 + r) * 32 + k] = word;
    }
    cx1 = nx1; cy1 = ny1; cx2 = nx2; cy2 = ny2; car = nar;
  }
}

// --- 6. greedy NMS (7 producers + 1 consumer) FUSED with re-rank ------------
#define GRP_N 63
#define RING 6
__global__ __launch_bounds__(512) void k_greedy(RPNParams p) {
  int t = blockIdx.x;
  int tid = threadIdx.x;
  __shared__ unsigned long long ring[RING * 1024];  // 48 KB
  __shared__ int ready[GRP_N];
  __shared__ int cons_s;
  __shared__ unsigned long long kw[32], aw[32], bw[32];
  __shared__ unsigned int prefA[33], prefB[33];
  volatile int* rdy = ready;
  volatile int* cons = &cons_s;
  const unsigned long long* MK = p.mask + (size_t)t * NPRE * 32;
  for (int i = tid; i < GRP_N; i += 512) ready[i] = 0;
  if (tid == 0) cons_s = 0;
  __syncthreads();

  int wave = tid >> 6, lane = tid & 63;
  if (wave >= 1) {
    // ---------------- producer waves (7) ----------------
    for (int g = wave - 1; g < GRP_N; g += 7) {
      while (g - *cons >= RING) __builtin_amdgcn_s_sleep(1);
      unsigned long long v[16];
#pragma unroll
      for (int k = 0; k < 16; k++) {
        int idx = k * 64 + lane;           // 0..1023
        int row = g * 32 + (idx >> 5);
        v[k] = (row < NPRE) ? MK[(size_t)row * 32 + (idx & 31)] : 0ull;
      }
      int slot = g % RING;
#pragma unroll
      for (int k = 0; k < 16; k++)
        ring[slot * 1024 + k * 64 + lane] = v[k];
      __threadfence_block();  // data visible before publish
      if (lane == 0) rdy[g] = 1;
    }
  } else {
    // ---------------- consumer wave ----------------
    unsigned long long supp = 0ull, keep = 0ull;  // lane j<32: word j
    for (int g = 0; g < GRP_N; g++) {
      while (rdy[g] == 0) { }  // busy-poll
      __threadfence_block();
      int slot = g % RING;
      int c = g >> 1;           // owner chunk (uniform scalar)
      int base = (g & 1) * 32;  // bit offset within the chunk word
      unsigned long long rv[32];
#pragma unroll
      for (int r = 0; r < 32; r++)
        rv[r] = ring[slot * 1024 + r * 32 + (lane & 31)];
      // broadcast supp[c]>>base (32-bit half) from lane c via readlane
      unsigned int sh = (unsigned int)(supp >> base);
      unsigned int s32 = (unsigned int)__builtin_amdgcn_readlane((int)sh, c);
      // branchless closure on ALL lanes (own rv; only lane c meaningful)
      unsigned int kg = 0;
#pragma unroll
      for (int r = 0; r < 32; r++) {
        unsigned int rvh = (unsigned int)(rv[r] >> base);
        bool kp = (s32 & (1u << r)) == 0u;
        kg |= kp ? (1u << r) : 0u;
        s32 |= kp ? rvh : 0u;
      }
      kg = (unsigned int)__builtin_amdgcn_readlane((int)kg, c);  // scalar
      // apply: OR kept rows' column words (kg is uniform scalar)
      unsigned long long acc0 = 0ull, acc1 = 0ull;
#pragma unroll
      for (int r = 0; r < 32; r += 2) {
        acc0 |= ((kg >> r) & 1u) ? rv[r] : 0ull;
        acc1 |= ((kg >> (r + 1)) & 1u) ? rv[r + 1] : 0ull;
      }
      supp |= acc0 | acc1;
      keep |= (lane == c) ? ((unsigned long long)kg << base) : 0ull;
      __threadfence_block();  // rv reads retired before freeing slot
      if (lane == 63) *cons = g + 1;
    }
    if (lane < 32) kw[lane] = keep;
  }
  __syncthreads();

  // ---------------- fused re-rank (all 8 waves) ----------------
  for (int ch = wave; ch < 32; ch += 8) {
    int i = ch * 64 + lane;
    bool inr = i < NPRE;
    bool kb = inr && ((kw[ch] >> lane) & 1ull);
    bool A = kb && (inr ? (p.selScores[(size_t)t * NPRE + i] > -0.5) : false);
    bool B = inr && !A;
    unsigned long long wa = __ballot(A);
    unsigned long long wb = __ballot(B);
    if (lane == 0) { aw[ch] = wa; bw[ch] = wb; }
  }
  __syncthreads();
  if (tid == 0) {
    unsigned int ca = 0, cb = 0;
    for (int w = 0; w < 32; w++) {
      prefA[w] = ca; ca += __popcll(aw[w]);
      prefB[w] = cb; cb += __popcll(bw[w]);
    }
    prefA[32] = ca; prefB[32] = cb;
  }
  __syncthreads();
  unsigned int KA = prefA[32];
  for (int i = tid; i < NPRE; i += 512) {
    int w = i >> 6, bpos = i & 63;
    unsigned long long below = (bpos == 0) ? 0ull : (~0ull >> (64 - bpos));
    bool kb = (kw[w] >> bpos) & 1ull;
    double s = p.selScores[(size_t)t * NPRE + i];
    bool A = kb && (s > -0.5);
    unsigned int slot;
    double outs;
    if (A) {
      slot = prefA[w] + (unsigned int)__popcll(aw[w] & below);
      outs = s;
    } else {
      slot = KA + prefB[w] + (unsigned int)__popcll(bw[w] & below);
      outs = -1.0;
    }
    if (slot < NPOST) {
      p.postScores[(size_t)t * NPOST + slot] = outs;
      const double* SB = p.selBoxes + ((size_t)t * NPRE + i) * 4;
      float* PB = p.postBoxes + ((size_t)t * NPOST + slot) * 4;
      PB[0] = (float)SB[0]; PB[1] = (float)SB[1];
      PB[2] = (float)SB[2]; PB[3] = (float)SB[3];
    }
  }
}

// --- 8a. final cross-level top-1000: k_rank-shaped counting-rank ------------
__global__ void k_finalA(RPNParams p) {
  int bx = blockIdx.x;
  int b = bx / 80;        // image 0..1
  int rem = bx % 80;
  int s = rem >> 2;       // j-slice 0..19
  int ec = rem & 3;       // e-chunk 0..3
  int j0 = s * 256;
  __shared__ unsigned long long kj[256];
  int tid = threadIdx.x;  // 256
  {
    int e = j0 + tid;
    unsigned long long v = 0ull;
    if (e < 5000) {
      int l = e / 1000, slot = e - l * 1000;
      int t = l * 2 + b;
      v = flip64_dev(p.postScores[(size_t)t * NPOST + slot]);
    }
    kj[tid] = v;
  }
  __syncthreads();
  int eidx[5];
  unsigned long long ke[5];
  unsigned int r[5];
#pragma unroll
  for (int k = 0; k < 5; k++) {
    int e = ec * 1280 + k * 256 + tid;
    eidx[k] = (e < 5000) ? e : -1;
    if (eidx[k] >= 0) {
      int l = e / 1000, slot = e - l * 1000;
      int t = l * 2 + b;
      ke[k] = flip64_dev(p.postScores[(size_t)t * NPOST + slot]);
    } else {
      ke[k] = 0ull;
    }
    r[k] = 0;
  }
  for (int j = 0; j < 256; j++) {
    unsigned long long vj = kj[j];
    int jg = j0 + j;
#pragma unroll
    for (int k = 0; k < 5; k++)
      r[k] += (vj > ke[k] || (vj == ke[k] && jg < eidx[k])) ? 1u : 0u;
  }
#pragma unroll
  for (int k = 0; k < 5; k++)
    if (eidx[k] >= 0)
      p.partial[((size_t)b * 20 + s) * 5000 + eidx[k]] = r[k];
}

// --- 8b. reduce ranks (20 slices), gather output boxes ----------------------
__global__ void k_finalB(RPNParams p) {
  int b = blockIdx.x / 5;
  int ch = blockIdx.x % 5;
  int tid = threadIdx.x;  // 1024
  if (tid < 1000) {
    int e = ch * 1000 + tid;
    unsigned int r = 0;
#pragma unroll
    for (int s = 0; s < 20; s++)
      r += p.partial[((size_t)b * 20 + s) * 5000 + e];
    if (r < NPOST) {
      int l = e / 1000, slot = e - l * 1000;
      int t = l * 2 + b;
      const float* PB = p.postBoxes + ((size_t)t * NPOST + slot) * 4;
      float* O = p.out + ((size_t)b * NPOST + r) * 4;
      O[0] = PB[0]; O[1] = PB[1]; O[2] = PB[2]; O[3] = PB[3];
    }
  }
}

extern "C" void kernel_launch(void* const* d_in, const int* in_sizes, int n_in,
                              void* d_out, int out_size, void* d_ws,
                              size_t ws_size, hipStream_t stream) {
  RPNParams p;
  bool interleaved = (n_in >= 2) && (in_sizes[1] == 4 * in_sizes[0]);
  for (int l = 0; l < 5; l++) {
    if (interleaved) {
      p.cls[l]  = (const float*)d_in[3 * l + 0];
      p.bbox[l] = (const float*)d_in[3 * l + 1];
      p.anc[l]  = (const float*)d_in[3 * l + 2];
    } else {
      p.cls[l]  = (const float*)d_in[l];
      p.bbox[l] = (const float*)d_in[5 + l];
      p.anc[l]  = (const float*)d_in[10 + l];
    }
  }
  char* w = (char*)d_ws;
  size_t off = 0;
  auto alloc = [&](size_t bytes) {
    off = (off + 255) & ~(size_t)255;
    void* r = w + off;
    off += bytes;
    return r;
  };
  p.mainCount = (unsigned int*)alloc(10 * 4);
  p.candCount = (unsigned int*)alloc(10 * 4);
  size_t zbytes = off;  // zeroed region: atomic counters only
  p.hist       = (unsigned int*)alloc((size_t)70 * 4096 * 4);
  p.Bstar      = (unsigned int*)alloc(10 * 4);
  p.mainEK     = (unsigned long long*)alloc((size_t)10 * 2048 * 8);
  p.candEK     = (unsigned long long*)alloc((size_t)10 * 8192 * 8);
  p.ekG        = (unsigned long long*)alloc((size_t)10 * 2048 * 8);
  p.partialR   = (unsigned int*)alloc((size_t)10 * 8 * 2048 * 4);
  p.selBoxes   = (double*)alloc((size_t)10 * NPRE * 4 * 8);
  p.selScores  = (double*)alloc((size_t)10 * NPRE * 8);
  p.mask       = (unsigned long long*)alloc((size_t)10 * NPRE * 32 * 8);
  p.postScores = (double*)alloc((size_t)10 * NPOST * 8);
  p.postBoxes  = (float*)alloc((size_t)10 * NPOST * 4 * 4);
  p.partial    = (unsigned int*)alloc((size_t)2 * 20 * 5000 * 4);
  p.out = (float*)d_out;
  (void)ws_size; (void)out_size;

  hipMemsetAsync(d_ws, 0, zbytes, stream);
  k_hist<<<dim3(70), dim3(1024), 0, stream>>>(p);
  k_find<<<dim3(8), dim3(1024), 0, stream>>>(p);
  k_compact<<<dim3(266), dim3(1024), 0, stream>>>(p);
  k_fill<<<dim3(10), dim3(256), 0, stream>>>(p);
  k_rank<<<dim3(80), dim3(256), 0, stream>>>(p);
  k_scatter<<<dim3(10), dim3(1024), 0, stream>>>(p);
  k_iou<<<dim3(250), dim3(640), 0, stream>>>(p);
  k_greedy<<<dim3(10), dim3(512), 0, stream>>>(p);
  k_finalA<<<dim3(160), dim3(256), 0, stream>>>(p);
  k_finalB<<<dim3(10), dim3(1024), 0, stream>>>(p);
}

// Round 14
// 447.955 us; speedup vs baseline: 1.0433x; 1.0433x over previous
//
#include <hip/hip_runtime.h>
#include <cmath>

// ---------------------------------------------------------------------------
// RPN head post-processing (mmdet GetBboxes-style), exact-semantics HIP port.
//
// Correctness: ordering-critical math fp64-exact (sigmoid, delta2bbox) or
// fp64-equivalent (IoU: fp32 filter + fp64 fallback band); top-k ordering on
// raw fp32 logit bits (monotone == fp64 sigmoid order; ties -> lower index).
//
// R13 PM: 12-bit buckets made the tie-bucket ~1200 els and k_fill's strip
// arrays spilled (VGPR_Count=16!) -> 125us scratch-bound on 10 blocks.
// R14: 14-bit buckets (16384 bins = 64 KB LDS hist, still zero global
// atomics; tie-bucket ~300 max) + k_fill reverted to the simple R10
// quadratic rank (no register strips -- was fast when nC is small).
// Bucket width only affects the main/cand partition; the exact counting-
// rank over ekG fixes the final order regardless.
// ---------------------------------------------------------------------------

#define NPRE 2000
#define NPOST 1000

static __device__ __forceinline__ unsigned int flipf_dev(float f) {
  unsigned int u = __float_as_uint(f);
  return (u & 0x80000000u) ? ~u : (u | 0x80000000u);
}
static __device__ __forceinline__ float unflipf_dev(unsigned int k) {
  unsigned int u = (k & 0x80000000u) ? (k ^ 0x80000000u) : ~k;
  return __uint_as_float(u);
}
static __device__ __forceinline__ unsigned long long flip64_dev(double d) {
  unsigned long long u = (unsigned long long)__double_as_longlong(d);
  return (u & 0x8000000000000000ull) ? ~u : (u | 0x8000000000000000ull);
}

struct RPNParams {
  const float* cls[5];
  const float* bbox[5];
  const float* anc[5];
  unsigned int* hist;          // [70][16384] private per-block 14-bit hists
  unsigned int* mainCount;     // [10]
  unsigned int* candCount;     // [10]
  unsigned int* Bstar;         // [10]
  unsigned long long* mainEK;  // [10][2048]  packed (key<<32)|~idx
  unsigned long long* candEK;  // [10][8192]
  unsigned long long* ekG;     // [10][2048]  assembled top-2000 (+pads)
  unsigned int* partialR;      // [10][8][2048] sliced ranks
  double* selBoxes;            // [10][2000][4]
  double* selScores;           // [10][2000]
  unsigned long long* mask;    // [10][2000][32]
  double* postScores;          // [10][1000]
  float* postBoxes;            // [10][1000][4]
  unsigned int* partial;       // [2][20][5000]
  float* out;                  // [2][1000][4]
};

__device__ __constant__ int c_NL[5]  = {201600, 50400, 12600, 3150, 819};
__device__ __constant__ int c_HW[5]  = {67200, 16800, 4200, 1050, 273};
// blocks-per-task at 2048 elements/block (levels 0..3 x 2 images) -- compact
__device__ __constant__ int c_BPT[8] = {99, 99, 25, 25, 7, 7, 2, 2};
// blocks-per-task at 8192 elements/block -- hist (total 70)
__device__ __constant__ int c_BPT12[8] = {25, 25, 7, 7, 2, 2, 1, 1};

static __device__ __forceinline__ void map_block(int bx, int& t, int& chunk) {
  int start = 0;
  t = 0;
  for (int k = 0; k < 8; k++) {
    if (bx < start + c_BPT[k]) { t = k; break; }
    start += c_BPT[k];
  }
  chunk = bx - start;
}
static __device__ __forceinline__ void map_block12(int bx, int& t, int& chunk) {
  int start = 0;
  t = 0;
  for (int k = 0; k < 8; k++) {
    if (bx < start + c_BPT12[k]) { t = k; break; }
    start += c_BPT12[k];
  }
  chunk = bx - start;
}

// --- 1. per-block PRIVATE 14-bit histogram (LDS atomics, no global atomics) -
__global__ __launch_bounds__(1024) void k_hist(RPNParams p) {
  __shared__ unsigned int lh[16384];  // 64 KB
  int t, chunk;
  map_block12(blockIdx.x, t, chunk);
  int l = t >> 1, b = t & 1;
  int N = c_NL[l], HW = c_HW[l];
  const float* cls = p.cls[l] + (size_t)b * 3 * HW;
  int tid = threadIdx.x;
  for (int i = tid; i < 16384; i += 1024) lh[i] = 0;
  __syncthreads();
  int base = chunk * 8192 + tid;
#pragma unroll
  for (int k = 0; k < 8; k++) {
    int n = base + k * 1024;
    if (n < N) {
      int a = n % 3, hw = n / 3;
      unsigned int key = flipf_dev(cls[a * HW + hw]);
      atomicAdd(&lh[key >> 18], 1u);
    }
  }
  __syncthreads();
  unsigned int* hout = p.hist + (size_t)blockIdx.x * 16384;
  for (int i = tid; i < 16384; i += 1024) hout[i] = lh[i];
}

// --- 2. reduce private hists + find threshold bucket B* (14-bit) ------------
__global__ __launch_bounds__(1024) void k_find(RPNParams p) {
  int t = blockIdx.x;  // 0..7
  __shared__ unsigned int H[16384];  // 64 KB
  __shared__ unsigned int S[1024];
  __shared__ int gsel;
  __shared__ unsigned int baseAbove;
  int tid = threadIdx.x;  // 1024
  int start = 0;
  for (int k = 0; k < t; k++) start += c_BPT12[k];
  int bpt = c_BPT12[t];
  for (int bin = tid; bin < 16384; bin += 1024) {
    unsigned int s = 0;
    for (int bb = 0; bb < bpt; bb++)
      s += p.hist[(size_t)(start + bb) * 16384 + bin];
    H[bin] = s;
  }
  __syncthreads();
  {
    unsigned int s = 0;
#pragma unroll
    for (int k = 0; k < 16; k++) s += H[tid * 16 + k];
    S[tid] = s;
  }
  __syncthreads();
  for (int off = 1; off < 1024; off <<= 1) {
    unsigned int add = (tid + off < 1024) ? S[tid + off] : 0u;
    __syncthreads();
    S[tid] += add;
    __syncthreads();
  }
  const unsigned int need = NPRE;
  if (S[tid] >= need && (tid == 1023 || S[tid + 1] < need)) {
    gsel = tid;
    baseAbove = (tid == 1023) ? 0u : S[tid + 1];
  }
  __syncthreads();
  if (tid == 0) {
    int gg = gsel;
    unsigned int c = baseAbove;
    int bstar = gg * 16;
    for (int bb = 15; bb >= 0; bb--) {
      c += H[gg * 16 + bb];
      if (c >= need) { bstar = gg * 16 + bb; break; }
    }
    p.Bstar[t] = (unsigned int)bstar;
  }
}

// --- 3. compaction: above-bucket -> main, == bucket -> cand (14-bit) --------
__global__ void k_compact(RPNParams p) {
  int t, chunk;
  map_block(blockIdx.x, t, chunk);
  int l = t >> 1, b = t & 1;
  int N = c_NL[l], HW = c_HW[l];
  const float* cls = p.cls[l] + (size_t)b * 3 * HW;
  unsigned int Bs = p.Bstar[t];
  int base = chunk * 2048 + threadIdx.x;
  for (int k = 0; k < 2; k++) {
    int n = base + k * 1024;
    if (n < N) {
      int a = n % 3, hw = n / 3;
      unsigned int key = flipf_dev(cls[a * HW + hw]);
      unsigned int hi = key >> 18;
      unsigned long long ek =
          ((unsigned long long)key << 32) | (unsigned int)(~(unsigned int)n);
      if (hi > Bs) {
        unsigned int pos = atomicAdd(&p.mainCount[t], 1u);
        if (pos < 2048u) p.mainEK[(size_t)t * 2048 + pos] = ek;
      } else if (hi == Bs) {
        unsigned int pos = atomicAdd(&p.candCount[t], 1u);
        if (pos < 8192u) p.candEK[(size_t)t * 8192 + pos] = ek;
      }
    }
  }
}

// --- 4a. fill ekG[t][2048]: exact top-2000 keys + pads ----------------------
// Simple quadratic cand-rank (nC <= ~300 at 14-bit buckets; broadcast global
// reads hit L1 -- this exact pattern was fast at R10).
__global__ void k_fill(RPNParams p) {
  int t = blockIdx.x;  // 0..9
  int l = t >> 1, b = t & 1;
  int N = c_NL[l], HW = c_HW[l];
  int tid = threadIdx.x;  // 256
  unsigned long long* ekG = p.ekG + (size_t)t * 2048;
  if (N >= NPRE) {
    unsigned int cGT = min(p.mainCount[t], 2000u);
    unsigned int nC = min(p.candCount[t], 8192u);
    unsigned int needIn = 2000u - cGT;
    for (unsigned int m = tid; m < cGT; m += 256)
      ekG[m] = p.mainEK[(size_t)t * 2048 + m];
    const unsigned long long* cek = p.candEK + (size_t)t * 8192;
    for (unsigned int e = tid; e < nC; e += 256) {
      unsigned long long ve = cek[e];
      unsigned int r = 0;
      for (unsigned int j = 0; j < nC; j++) r += (cek[j] > ve) ? 1u : 0u;
      if (r < needIn) ekG[cGT + r] = ve;
    }
    for (unsigned int r2 = 2000u + tid; r2 < 2048u; r2 += 256)
      ekG[r2] = (unsigned long long)(unsigned int)(~r2);
  } else {
    // level 4 (N=819): pad path -- key 0 pads below all finite logits
    const float* cls = p.cls[l] + (size_t)b * 3 * HW;
    for (int r = tid; r < 2048; r += 256) {
      if (r < N) {
        int a = r % 3, hw = r / 3;
        unsigned int key = flipf_dev(cls[a * HW + hw]);
        ekG[r] = ((unsigned long long)key << 32) |
                 (unsigned int)(~(unsigned int)r);
      } else {
        ekG[r] = (unsigned long long)(unsigned int)(~(unsigned int)r);
      }
    }
  }
}

// --- 4b. sliced counting-rank: 8 slices x 10 tasks --------------------------
__global__ void k_rank(RPNParams p) {
  int t = blockIdx.x >> 3;
  int s = blockIdx.x & 7;
  int tid = threadIdx.x;  // 256
  __shared__ unsigned long long sl[256];
  const unsigned long long* ekG = p.ekG + (size_t)t * 2048;
  sl[tid] = ekG[s * 256 + tid];
  __syncthreads();
  unsigned long long ve[8];
  unsigned int r[8];
#pragma unroll
  for (int k = 0; k < 8; k++) {
    ve[k] = ekG[k * 256 + tid];
    r[k] = 0;
  }
  for (int j = 0; j < 256; j++) {
    unsigned long long vj = sl[j];
#pragma unroll
    for (int k = 0; k < 8; k++) r[k] += (vj > ve[k]) ? 1u : 0u;
  }
  unsigned int* out = p.partialR + ((size_t)t * 8 + s) * 2048;
#pragma unroll
  for (int k = 0; k < 8; k++) out[k * 256 + tid] = r[k];
}

// --- 4c. scatter by total rank + fp64 decode --------------------------------
__global__ void k_scatter(RPNParams p) {
  int t = blockIdx.x;  // 0..9
  int l = t >> 1, b = t & 1;
  int HW = c_HW[l];
  int tid = threadIdx.x;  // 1024
  __shared__ unsigned long long srt[2048];
  const unsigned long long* ekG = p.ekG + (size_t)t * 2048;
  for (int e = tid; e < 2048; e += 1024) {
    unsigned int rk = 0;
#pragma unroll
    for (int s = 0; s < 8; s++)
      rk += p.partialR[((size_t)t * 8 + s) * 2048 + e];
    srt[rk] = ekG[e];
  }
  __syncthreads();

  const double RCLIP = fabs(log(16.0 / 1000.0));  // mmdet wh_ratio_clip
  const float* bbx = p.bbox[l] + (size_t)b * 12 * HW;
  const float* anc = p.anc[l];
  for (int r = tid; r < NPRE; r += 1024) {
    unsigned long long v = srt[r];
    unsigned int key = (unsigned int)(v >> 32);
    double* SB = p.selBoxes + ((size_t)t * NPRE + r) * 4;
    if (key == 0u) {  // pad: zero anchors/deltas -> zero box, score -1
      SB[0] = 0.0; SB[1] = 0.0; SB[2] = 0.0; SB[3] = 0.0;
      p.selScores[(size_t)t * NPRE + r] = -1.0;
    } else {
      unsigned int idx = ~(unsigned int)(v & 0xFFFFFFFFull);
      int a = (int)(idx % 3u);
      int hw = (int)(idx / 3u);
      double d0 = (double)bbx[(a * 4 + 0) * HW + hw];
      double d1 = (double)bbx[(a * 4 + 1) * HW + hw];
      double d2 = (double)bbx[(a * 4 + 2) * HW + hw];
      double d3 = (double)bbx[(a * 4 + 3) * HW + hw];
      double a0 = (double)anc[(size_t)idx * 4 + 0];
      double a1 = (double)anc[(size_t)idx * 4 + 1];
      double a2 = (double)anc[(size_t)idx * 4 + 2];
      double a3 = (double)anc[(size_t)idx * 4 + 3];
      double dw = fmin(fmax(d2, -RCLIP), RCLIP);
      double dh = fmin(fmax(d3, -RCLIP), RCLIP);
      double pw = a2 - a0, ph = a3 - a1;
      double px = (a0 + a2) * 0.5, py = (a1 + a3) * 0.5;
      double gw = pw * exp(dw), gh = ph * exp(dh);
      double gx = px + pw * d0, gy = py + ph * d1;
      double x1 = fmin(fmax(gx - 0.5 * gw, 0.0), 1344.0);
      double y1 = fmin(fmax(gy - 0.5 * gh, 0.0), 800.0);
      double x2 = fmin(fmax(gx + 0.5 * gw, 0.0), 1344.0);
      double y2 = fmin(fmax(gy + 0.5 * gh, 0.0), 800.0);
      SB[0] = x1; SB[1] = y1; SB[2] = x2; SB[3] = y2;
      float f = unflipf_dev(key);
      p.selScores[(size_t)t * NPRE + r] = 1.0 / (1.0 + exp(-(double)f));
    }
  }
}

// --- 5. IoU -> suppression bitmask. 8 rows share each column load. ----------
__global__ __launch_bounds__(640) void k_iou(RPNParams p) {
  int bx = blockIdx.x;
  int t = bx / 25;
  int q = bx % 25;
  __shared__ float X1[2048], Y1[2048], X2[2048], Y2[2048], AR[2048];
  const double* SB = p.selBoxes + (size_t)t * NPRE * 4;
  for (int i = threadIdx.x; i < 2048; i += 640) {
    float x1 = 0.f, y1 = 0.f, x2 = 0.f, y2 = 0.f;
    if (i < NPRE) {
      x1 = (float)SB[i * 4 + 0]; y1 = (float)SB[i * 4 + 1];
      x2 = (float)SB[i * 4 + 2]; y2 = (float)SB[i * 4 + 3];
    }
    X1[i] = x1; Y1[i] = y1; X2[i] = x2; Y2[i] = y2;
    AR[i] = (x2 - x1) * (y2 - y1);
  }
  __syncthreads();
  int wave = threadIdx.x >> 6, lane = threadIdx.x & 63;
  int g = q + 25 * wave;  // [0,250)
  int i0 = g * 8;
  float x1i[8], y1i[8], x2i[8], y2i[8], ai[8];
#pragma unroll
  for (int r = 0; r < 8; r++) {
    int i = i0 + r;
    x1i[r] = X1[i]; y1i[r] = Y1[i]; x2i[r] = X2[i]; y2i[r] = Y2[i];
    ai[r] = AR[i];
  }
  int c0 = i0 >> 6;
  int j0 = c0 * 64 + lane;
  float cx1 = X1[j0], cy1 = Y1[j0], cx2 = X2[j0], cy2 = Y2[j0], car = AR[j0];
  for (int k = c0; k < 32; k++) {
    float nx1 = 0.f, ny1 = 0.f, nx2 = 0.f, ny2 = 0.f, nar = 0.f;
    if (k + 1 < 32) {  // prefetch next column word
      int jn = (k + 1) * 64 + lane;
      nx1 = X1[jn]; ny1 = Y1[jn]; nx2 = X2[jn]; ny2 = Y2[jn];
      nar = AR[jn];
    }
    int j = k * 64 + lane;
    bool jin = j < NPRE;
    bool pred[8], need[8];
    bool needAny = false;
#pragma unroll
    for (int r = 0; r < 8; r++) {
      int i = i0 + r;
      bool valid = jin && (j > i);
      float lx = fmaxf(x1i[r], cx1), ly = fmaxf(y1i[r], cy1);
      float rx = fminf(x2i[r], cx2), ry = fminf(y2i[r], cy2);
      float w = fmaxf(rx - lx, 0.0f), h = fmaxf(ry - ly, 0.0f);
      float inter = w * h;
      float uni = fmaxf(ai[r] + car - inter, 1e-6f);
      float diff = inter - 0.7f * uni;
      pred[r] = valid && (diff > 0.0f);
      need[r] = valid && (fabsf(diff) <= 4.0f + 1e-5f * uni);
      needAny |= need[r];
    }
    if (__any(needAny)) {  // rare: exact fp64 near the 0.7 boundary
#pragma unroll
      for (int r = 0; r < 8; r++) {
        if (need[r]) {
          int i = i0 + r;
          double a0 = SB[i * 4 + 0], b0 = SB[i * 4 + 1];
          double a2 = SB[i * 4 + 2], b2 = SB[i * 4 + 3];
          double c0d = SB[j * 4 + 0], d0 = SB[j * 4 + 1];
          double c2 = SB[j * 4 + 2], d2 = SB[j * 4 + 3];
          double dai = (a2 - a0) * (b2 - b0);
          double daj = (c2 - c0d) * (d2 - d0);
          double lxd = fmax(a0, c0d), lyd = fmax(b0, d0);
          double rxd = fmin(a2, c2), ryd = fmin(b2, d2);
          double wd = fmax(rxd - lxd, 0.0), hd = fmax(ryd - lyd, 0.0);
          double interd = wd * hd;
          double unid = fmax(dai + daj - interd, 1e-6);
          pred[r] = (interd / unid) > 0.7;
        }
      }
    }
#pragma unroll
    for (int r = 0; r < 8; r++) {
      unsigned long long word = __ballot(pred[r]);
      if (lane == 0) p.mask[((size_t)t * NPRE + i0 + r) * 32 + k] = word;
    }
    cx1 = nx1; cy1 = ny1; cx2 = nx2; cy2 = ny2; car = nar;
  }
}

// --- 6. greedy NMS (7 producers + 1 consumer) FUSED with re-rank ------------
#define GRP_N 63
#define RING 6
__global__ __launch_bounds__(512) void k_greedy(RPNParams p) {
  int t = blockIdx.x;
  int tid = threadIdx.x;
  __shared__ unsigned long long ring[RING * 1024];  // 48 KB
  __shared__ int ready[GRP_N];
  __shared__ int cons_s;
  __shared__ unsigned long long kw[32], aw[32], bw[32];
  __shared__ unsigned int prefA[33], prefB[33];
  volatile int* rdy = ready;
  volatile int* cons = &cons_s;
  const unsigned long long* MK = p.mask + (size_t)t * NPRE * 32;
  for (int i = tid; i < GRP_N; i += 512) ready[i] = 0;
  if (tid == 0) cons_s = 0;
  __syncthreads();

  int wave = tid >> 6, lane = tid & 63;
  if (wave >= 1) {
    // ---------------- producer waves (7) ----------------
    for (int g = wave - 1; g < GRP_N; g += 7) {
      while (g - *cons >= RING) __builtin_amdgcn_s_sleep(1);
      unsigned long long v[16];
#pragma unroll
      for (int k = 0; k < 16; k++) {
        int idx = k * 64 + lane;           // 0..1023
        int row = g * 32 + (idx >> 5);
        v[k] = (row < NPRE) ? MK[(size_t)row * 32 + (idx & 31)] : 0ull;
      }
      int slot = g % RING;
#pragma unroll
      for (int k = 0; k < 16; k++)
        ring[slot * 1024 + k * 64 + lane] = v[k];
      __threadfence_block();  // data visible before publish
      if (lane == 0) rdy[g] = 1;
    }
  } else {
    // ---------------- consumer wave ----------------
    unsigned long long supp = 0ull, keep = 0ull;  // lane j<32: word j
    for (int g = 0; g < GRP_N; g++) {
      while (rdy[g] == 0) { }  // busy-poll
      __threadfence_block();
      int slot = g % RING;
      int c = g >> 1;           // owner chunk (uniform scalar)
      int base = (g & 1) * 32;  // bit offset within the chunk word
      unsigned long long rv[32];
#pragma unroll
      for (int r = 0; r < 32; r++)
        rv[r] = ring[slot * 1024 + r * 32 + (lane & 31)];
      // broadcast supp[c]>>base (32-bit half) from lane c via readlane
      unsigned int sh = (unsigned int)(supp >> base);
      unsigned int s32 = (unsigned int)__builtin_amdgcn_readlane((int)sh, c);
      // branchless closure on ALL lanes (own rv; only lane c meaningful)
      unsigned int kg = 0;
#pragma unroll
      for (int r = 0; r < 32; r++) {
        unsigned int rvh = (unsigned int)(rv[r] >> base);
        bool kp = (s32 & (1u << r)) == 0u;
        kg |= kp ? (1u << r) : 0u;
        s32 |= kp ? rvh : 0u;
      }
      kg = (unsigned int)__builtin_amdgcn_readlane((int)kg, c);  // scalar
      // apply: OR kept rows' column words (kg is uniform scalar)
      unsigned long long acc0 = 0ull, acc1 = 0ull;
#pragma unroll
      for (int r = 0; r < 32; r += 2) {
        acc0 |= ((kg >> r) & 1u) ? rv[r] : 0ull;
        acc1 |= ((kg >> (r + 1)) & 1u) ? rv[r + 1] : 0ull;
      }
      supp |= acc0 | acc1;
      keep |= (lane == c) ? ((unsigned long long)kg << base) : 0ull;
      __threadfence_block();  // rv reads retired before freeing slot
      if (lane == 63) *cons = g + 1;
    }
    if (lane < 32) kw[lane] = keep;
  }
  __syncthreads();

  // ---------------- fused re-rank (all 8 waves) ----------------
  for (int ch = wave; ch < 32; ch += 8) {
    int i = ch * 64 + lane;
    bool inr = i < NPRE;
    bool kb = inr && ((kw[ch] >> lane) & 1ull);
    bool A = kb && (inr ? (p.selScores[(size_t)t * NPRE + i] > -0.5) : false);
    bool B = inr && !A;
    unsigned long long wa = __ballot(A);
    unsigned long long wb = __ballot(B);
    if (lane == 0) { aw[ch] = wa; bw[ch] = wb; }
  }
  __syncthreads();
  if (tid == 0) {
    unsigned int ca = 0, cb = 0;
    for (int w = 0; w < 32; w++) {
      prefA[w] = ca; ca += __popcll(aw[w]);
      prefB[w] = cb; cb += __popcll(bw[w]);
    }
    prefA[32] = ca; prefB[32] = cb;
  }
  __syncthreads();
  unsigned int KA = prefA[32];
  for (int i = tid; i < NPRE; i += 512) {
    int w = i >> 6, bpos = i & 63;
    unsigned long long below = (bpos == 0) ? 0ull : (~0ull >> (64 - bpos));
    bool kb = (kw[w] >> bpos) & 1ull;
    double s = p.selScores[(size_t)t * NPRE + i];
    bool A = kb && (s > -0.5);
    unsigned int slot;
    double outs;
    if (A) {
      slot = prefA[w] + (unsigned int)__popcll(aw[w] & below);
      outs = s;
    } else {
      slot = KA + prefB[w] + (unsigned int)__popcll(bw[w] & below);
      outs = -1.0;
    }
    if (slot < NPOST) {
      p.postScores[(size_t)t * NPOST + slot] = outs;
      const double* SB = p.selBoxes + ((size_t)t * NPRE + i) * 4;
      float* PB = p.postBoxes + ((size_t)t * NPOST + slot) * 4;
      PB[0] = (float)SB[0]; PB[1] = (float)SB[1];
      PB[2] = (float)SB[2]; PB[3] = (float)SB[3];
    }
  }
}

// --- 8a. final cross-level top-1000: k_rank-shaped counting-rank ------------
__global__ void k_finalA(RPNParams p) {
  int bx = blockIdx.x;
  int b = bx / 80;        // image 0..1
  int rem = bx % 80;
  int s = rem >> 2;       // j-slice 0..19
  int ec = rem & 3;       // e-chunk 0..3
  int j0 = s * 256;
  __shared__ unsigned long long kj[256];
  int tid = threadIdx.x;  // 256
  {
    int e = j0 + tid;
    unsigned long long v = 0ull;
    if (e < 5000) {
      int l = e / 1000, slot = e - l * 1000;
      int t = l * 2 + b;
      v = flip64_dev(p.postScores[(size_t)t * NPOST + slot]);
    }
    kj[tid] = v;
  }
  __syncthreads();
  int eidx[5];
  unsigned long long ke[5];
  unsigned int r[5];
#pragma unroll
  for (int k = 0; k < 5; k++) {
    int e = ec * 1280 + k * 256 + tid;
    eidx[k] = (e < 5000) ? e : -1;
    if (eidx[k] >= 0) {
      int l = e / 1000, slot = e - l * 1000;
      int t = l * 2 + b;
      ke[k] = flip64_dev(p.postScores[(size_t)t * NPOST + slot]);
    } else {
      ke[k] = 0ull;
    }
    r[k] = 0;
  }
  for (int j = 0; j < 256; j++) {
    unsigned long long vj = kj[j];
    int jg = j0 + j;
#pragma unroll
    for (int k = 0; k < 5; k++)
      r[k] += (vj > ke[k] || (vj == ke[k] && jg < eidx[k])) ? 1u : 0u;
  }
#pragma unroll
  for (int k = 0; k < 5; k++)
    if (eidx[k] >= 0)
      p.partial[((size_t)b * 20 + s) * 5000 + eidx[k]] = r[k];
}

// --- 8b. reduce ranks (20 slices), gather output boxes ----------------------
__global__ void k_finalB(RPNParams p) {
  int b = blockIdx.x / 5;
  int ch = blockIdx.x % 5;
  int tid = threadIdx.x;  // 1024
  if (tid < 1000) {
    int e = ch * 1000 + tid;
    unsigned int r = 0;
#pragma unroll
    for (int s = 0; s < 20; s++)
      r += p.partial[((size_t)b * 20 + s) * 5000 + e];
    if (r < NPOST) {
      int l = e / 1000, slot = e - l * 1000;
      int t = l * 2 + b;
      const float* PB = p.postBoxes + ((size_t)t * NPOST + slot) * 4;
      float* O = p.out + ((size_t)b * NPOST + r) * 4;
      O[0] = PB[0]; O[1] = PB[1]; O[2] = PB[2]; O[3] = PB[3];
    }
  }
}

extern "C" void kernel_launch(void* const* d_in, const int* in_sizes, int n_in,
                              void* d_out, int out_size, void* d_ws,
                              size_t ws_size, hipStream_t stream) {
  RPNParams p;
  bool interleaved = (n_in >= 2) && (in_sizes[1] == 4 * in_sizes[0]);
  for (int l = 0; l < 5; l++) {
    if (interleaved) {
      p.cls[l]  = (const float*)d_in[3 * l + 0];
      p.bbox[l] = (const float*)d_in[3 * l + 1];
      p.anc[l]  = (const float*)d_in[3 * l + 2];
    } else {
      p.cls[l]  = (const float*)d_in[l];
      p.bbox[l] = (const float*)d_in[5 + l];
      p.anc[l]  = (const float*)d_in[10 + l];
    }
  }
  char* w = (char*)d_ws;
  size_t off = 0;
  auto alloc = [&](size_t bytes) {
    off = (off + 255) & ~(size_t)255;
    void* r = w + off;
    off += bytes;
    return r;
  };
  p.mainCount = (unsigned int*)alloc(10 * 4);
  p.candCount = (unsigned int*)alloc(10 * 4);
  size_t zbytes = off;  // zeroed region: atomic counters only
  p.hist       = (unsigned int*)alloc((size_t)70 * 16384 * 4);
  p.Bstar      = (unsigned int*)alloc(10 * 4);
  p.mainEK     = (unsigned long long*)alloc((size_t)10 * 2048 * 8);
  p.candEK     = (unsigned long long*)alloc((size_t)10 * 8192 * 8);
  p.ekG        = (unsigned long long*)alloc((size_t)10 * 2048 * 8);
  p.partialR   = (unsigned int*)alloc((size_t)10 * 8 * 2048 * 4);
  p.selBoxes   = (double*)alloc((size_t)10 * NPRE * 4 * 8);
  p.selScores  = (double*)alloc((size_t)10 * NPRE * 8);
  p.mask       = (unsigned long long*)alloc((size_t)10 * NPRE * 32 * 8);
  p.postScores = (double*)alloc((size_t)10 * NPOST * 8);
  p.postBoxes  = (float*)alloc((size_t)10 * NPOST * 4 * 4);
  p.partial    = (unsigned int*)alloc((size_t)2 * 20 * 5000 * 4);
  p.out = (float*)d_out;
  (void)ws_size; (void)out_size;

  hipMemsetAsync(d_ws, 0, zbytes, stream);
  k_hist<<<dim3(70), dim3(1024), 0, stream>>>(p);
  k_find<<<dim3(8), dim3(1024), 0, stream>>>(p);
  k_compact<<<dim3(266), dim3(1024), 0, stream>>>(p);
  k_fill<<<dim3(10), dim3(256), 0, stream>>>(p);
  k_rank<<<dim3(80), dim3(256), 0, stream>>>(p);
  k_scatter<<<dim3(10), dim3(1024), 0, stream>>>(p);
  k_iou<<<dim3(250), dim3(640), 0, stream>>>(p);
  k_greedy<<<dim3(10), dim3(512), 0, stream>>>(p);
  k_finalA<<<dim3(160), dim3(256), 0, stream>>>(p);
  k_finalB<<<dim3(10), dim3(1024), 0, stream>>>(p);
}

// Round 15
// 389.605 us; speedup vs baseline: 1.1995x; 1.1498x over previous
//
#include <hip/hip_runtime.h>
#include <cmath>

// ---------------------------------------------------------------------------
// RPN head post-processing (mmdet GetBboxes-style), exact-semantics HIP port.
//
// Correctness: ordering-critical math fp64-exact (sigmoid, delta2bbox) or
// fp64-equivalent (IoU: fp32 filter + fp64 fallback band); top-k ordering on
// raw fp32 logit bits (monotone == fp64 sigmoid order; ties -> lower index).
//
// R14 PM: k_find was 65us -- 8 blocks, each thread doing 16 bins x 25
// private-hist loads in a variable-trip dependent chain (~400 serial loads
// x 400cy). R15: reduction split into k_hred (8 tasks x 16 slices = 128
// blocks, 1 bin/thread, 4-way unrolled independent loads -> histT[8][16384]);
// k_find now just reads the reduced hist coalesced. Everything else as R14.
// ---------------------------------------------------------------------------

#define NPRE 2000
#define NPOST 1000

static __device__ __forceinline__ unsigned int flipf_dev(float f) {
  unsigned int u = __float_as_uint(f);
  return (u & 0x80000000u) ? ~u : (u | 0x80000000u);
}
static __device__ __forceinline__ float unflipf_dev(unsigned int k) {
  unsigned int u = (k & 0x80000000u) ? (k ^ 0x80000000u) : ~k;
  return __uint_as_float(u);
}
static __device__ __forceinline__ unsigned long long flip64_dev(double d) {
  unsigned long long u = (unsigned long long)__double_as_longlong(d);
  return (u & 0x8000000000000000ull) ? ~u : (u | 0x8000000000000000ull);
}

struct RPNParams {
  const float* cls[5];
  const float* bbox[5];
  const float* anc[5];
  unsigned int* hist;          // [70][16384] private per-block 14-bit hists
  unsigned int* histT;         // [8][16384] per-task reduced hists
  unsigned int* mainCount;     // [10]
  unsigned int* candCount;     // [10]
  unsigned int* Bstar;         // [10]
  unsigned long long* mainEK;  // [10][2048]  packed (key<<32)|~idx
  unsigned long long* candEK;  // [10][8192]
  unsigned long long* ekG;     // [10][2048]  assembled top-2000 (+pads)
  unsigned int* partialR;      // [10][8][2048] sliced ranks
  double* selBoxes;            // [10][2000][4]
  double* selScores;           // [10][2000]
  unsigned long long* mask;    // [10][2000][32]
  double* postScores;          // [10][1000]
  float* postBoxes;            // [10][1000][4]
  unsigned int* partial;       // [2][20][5000]
  float* out;                  // [2][1000][4]
};

__device__ __constant__ int c_NL[5]  = {201600, 50400, 12600, 3150, 819};
__device__ __constant__ int c_HW[5]  = {67200, 16800, 4200, 1050, 273};
// blocks-per-task at 2048 elements/block (levels 0..3 x 2 images) -- compact
__device__ __constant__ int c_BPT[8] = {99, 99, 25, 25, 7, 7, 2, 2};
// blocks-per-task at 8192 elements/block -- hist (total 70)
__device__ __constant__ int c_BPT12[8] = {25, 25, 7, 7, 2, 2, 1, 1};
__device__ __constant__ int c_HSTART[8] = {0, 25, 50, 57, 64, 66, 68, 69};

static __device__ __forceinline__ void map_block(int bx, int& t, int& chunk) {
  int start = 0;
  t = 0;
  for (int k = 0; k < 8; k++) {
    if (bx < start + c_BPT[k]) { t = k; break; }
    start += c_BPT[k];
  }
  chunk = bx - start;
}
static __device__ __forceinline__ void map_block12(int bx, int& t, int& chunk) {
  int start = 0;
  t = 0;
  for (int k = 0; k < 8; k++) {
    if (bx < start + c_BPT12[k]) { t = k; break; }
    start += c_BPT12[k];
  }
  chunk = bx - start;
}

// --- 1. per-block PRIVATE 14-bit histogram (LDS atomics, no global atomics) -
__global__ __launch_bounds__(1024) void k_hist(RPNParams p) {
  __shared__ unsigned int lh[16384];  // 64 KB
  int t, chunk;
  map_block12(blockIdx.x, t, chunk);
  int l = t >> 1, b = t & 1;
  int N = c_NL[l], HW = c_HW[l];
  const float* cls = p.cls[l] + (size_t)b * 3 * HW;
  int tid = threadIdx.x;
  for (int i = tid; i < 16384; i += 1024) lh[i] = 0;
  __syncthreads();
  int base = chunk * 8192 + tid;
#pragma unroll
  for (int k = 0; k < 8; k++) {
    int n = base + k * 1024;
    if (n < N) {
      int a = n % 3, hw = n / 3;
      unsigned int key = flipf_dev(cls[a * HW + hw]);
      atomicAdd(&lh[key >> 18], 1u);
    }
  }
  __syncthreads();
  unsigned int* hout = p.hist + (size_t)blockIdx.x * 16384;
  for (int i = tid; i < 16384; i += 1024) hout[i] = lh[i];
}

// --- 1b. reduce private hists -> per-task hist (128 blocks, 1 bin/thread) ---
__global__ __launch_bounds__(1024) void k_hred(RPNParams p) {
  int t = blockIdx.x >> 4;       // task 0..7
  int slice = blockIdx.x & 15;   // 0..15
  int bin = slice * 1024 + threadIdx.x;
  int start = c_HSTART[t];
  int bpt = c_BPT12[t];
  unsigned int s0 = 0, s1 = 0, s2 = 0, s3 = 0;
  int bb = 0;
  for (; bb + 4 <= bpt; bb += 4) {
    s0 += p.hist[(size_t)(start + bb + 0) * 16384 + bin];
    s1 += p.hist[(size_t)(start + bb + 1) * 16384 + bin];
    s2 += p.hist[(size_t)(start + bb + 2) * 16384 + bin];
    s3 += p.hist[(size_t)(start + bb + 3) * 16384 + bin];
  }
  for (; bb < bpt; bb++) s0 += p.hist[(size_t)(start + bb) * 16384 + bin];
  p.histT[(size_t)t * 16384 + bin] = s0 + s1 + s2 + s3;
}

// --- 2. find threshold bucket B* per task (reads reduced hist) --------------
__global__ __launch_bounds__(1024) void k_find(RPNParams p) {
  int t = blockIdx.x;  // 0..7
  __shared__ unsigned int H[16384];  // 64 KB
  __shared__ unsigned int S[1024];
  __shared__ int gsel;
  __shared__ unsigned int baseAbove;
  int tid = threadIdx.x;  // 1024
  const unsigned int* hT = p.histT + (size_t)t * 16384;
  for (int bin = tid; bin < 16384; bin += 1024) H[bin] = hT[bin];
  __syncthreads();
  {
    unsigned int s = 0;
#pragma unroll
    for (int k = 0; k < 16; k++) s += H[tid * 16 + k];
    S[tid] = s;
  }
  __syncthreads();
  for (int off = 1; off < 1024; off <<= 1) {
    unsigned int add = (tid + off < 1024) ? S[tid + off] : 0u;
    __syncthreads();
    S[tid] += add;
    __syncthreads();
  }
  const unsigned int need = NPRE;
  if (S[tid] >= need && (tid == 1023 || S[tid + 1] < need)) {
    gsel = tid;
    baseAbove = (tid == 1023) ? 0u : S[tid + 1];
  }
  __syncthreads();
  if (tid == 0) {
    int gg = gsel;
    unsigned int c = baseAbove;
    int bstar = gg * 16;
    for (int bb = 15; bb >= 0; bb--) {
      c += H[gg * 16 + bb];
      if (c >= need) { bstar = gg * 16 + bb; break; }
    }
    p.Bstar[t] = (unsigned int)bstar;
  }
}

// --- 3. compaction: above-bucket -> main, == bucket -> cand (14-bit) --------
__global__ void k_compact(RPNParams p) {
  int t, chunk;
  map_block(blockIdx.x, t, chunk);
  int l = t >> 1, b = t & 1;
  int N = c_NL[l], HW = c_HW[l];
  const float* cls = p.cls[l] + (size_t)b * 3 * HW;
  unsigned int Bs = p.Bstar[t];
  int base = chunk * 2048 + threadIdx.x;
  for (int k = 0; k < 2; k++) {
    int n = base + k * 1024;
    if (n < N) {
      int a = n % 3, hw = n / 3;
      unsigned int key = flipf_dev(cls[a * HW + hw]);
      unsigned int hi = key >> 18;
      unsigned long long ek =
          ((unsigned long long)key << 32) | (unsigned int)(~(unsigned int)n);
      if (hi > Bs) {
        unsigned int pos = atomicAdd(&p.mainCount[t], 1u);
        if (pos < 2048u) p.mainEK[(size_t)t * 2048 + pos] = ek;
      } else if (hi == Bs) {
        unsigned int pos = atomicAdd(&p.candCount[t], 1u);
        if (pos < 8192u) p.candEK[(size_t)t * 8192 + pos] = ek;
      }
    }
  }
}

// --- 4a. fill ekG[t][2048]: exact top-2000 keys + pads ----------------------
__global__ void k_fill(RPNParams p) {
  int t = blockIdx.x;  // 0..9
  int l = t >> 1, b = t & 1;
  int N = c_NL[l], HW = c_HW[l];
  int tid = threadIdx.x;  // 256
  unsigned long long* ekG = p.ekG + (size_t)t * 2048;
  if (N >= NPRE) {
    unsigned int cGT = min(p.mainCount[t], 2000u);
    unsigned int nC = min(p.candCount[t], 8192u);
    unsigned int needIn = 2000u - cGT;
    for (unsigned int m = tid; m < cGT; m += 256)
      ekG[m] = p.mainEK[(size_t)t * 2048 + m];
    const unsigned long long* cek = p.candEK + (size_t)t * 8192;
    for (unsigned int e = tid; e < nC; e += 256) {
      unsigned long long ve = cek[e];
      unsigned int r = 0;
      for (unsigned int j = 0; j < nC; j++) r += (cek[j] > ve) ? 1u : 0u;
      if (r < needIn) ekG[cGT + r] = ve;
    }
    for (unsigned int r2 = 2000u + tid; r2 < 2048u; r2 += 256)
      ekG[r2] = (unsigned long long)(unsigned int)(~r2);
  } else {
    // level 4 (N=819): pad path -- key 0 pads below all finite logits
    const float* cls = p.cls[l] + (size_t)b * 3 * HW;
    for (int r = tid; r < 2048; r += 256) {
      if (r < N) {
        int a = r % 3, hw = r / 3;
        unsigned int key = flipf_dev(cls[a * HW + hw]);
        ekG[r] = ((unsigned long long)key << 32) |
                 (unsigned int)(~(unsigned int)r);
      } else {
        ekG[r] = (unsigned long long)(unsigned int)(~(unsigned int)r);
      }
    }
  }
}

// --- 4b. sliced counting-rank: 8 slices x 10 tasks --------------------------
__global__ void k_rank(RPNParams p) {
  int t = blockIdx.x >> 3;
  int s = blockIdx.x & 7;
  int tid = threadIdx.x;  // 256
  __shared__ unsigned long long sl[256];
  const unsigned long long* ekG = p.ekG + (size_t)t * 2048;
  sl[tid] = ekG[s * 256 + tid];
  __syncthreads();
  unsigned long long ve[8];
  unsigned int r[8];
#pragma unroll
  for (int k = 0; k < 8; k++) {
    ve[k] = ekG[k * 256 + tid];
    r[k] = 0;
  }
  for (int j = 0; j < 256; j++) {
    unsigned long long vj = sl[j];
#pragma unroll
    for (int k = 0; k < 8; k++) r[k] += (vj > ve[k]) ? 1u : 0u;
  }
  unsigned int* out = p.partialR + ((size_t)t * 8 + s) * 2048;
#pragma unroll
  for (int k = 0; k < 8; k++) out[k * 256 + tid] = r[k];
}

// --- 4c. scatter by total rank + fp64 decode --------------------------------
__global__ void k_scatter(RPNParams p) {
  int t = blockIdx.x;  // 0..9
  int l = t >> 1, b = t & 1;
  int HW = c_HW[l];
  int tid = threadIdx.x;  // 1024
  __shared__ unsigned long long srt[2048];
  const unsigned long long* ekG = p.ekG + (size_t)t * 2048;
  for (int e = tid; e < 2048; e += 1024) {
    unsigned int rk = 0;
#pragma unroll
    for (int s = 0; s < 8; s++)
      rk += p.partialR[((size_t)t * 8 + s) * 2048 + e];
    srt[rk] = ekG[e];
  }
  __syncthreads();

  const double RCLIP = fabs(log(16.0 / 1000.0));  // mmdet wh_ratio_clip
  const float* bbx = p.bbox[l] + (size_t)b * 12 * HW;
  const float* anc = p.anc[l];
  for (int r = tid; r < NPRE; r += 1024) {
    unsigned long long v = srt[r];
    unsigned int key = (unsigned int)(v >> 32);
    double* SB = p.selBoxes + ((size_t)t * NPRE + r) * 4;
    if (key == 0u) {  // pad: zero anchors/deltas -> zero box, score -1
      SB[0] = 0.0; SB[1] = 0.0; SB[2] = 0.0; SB[3] = 0.0;
      p.selScores[(size_t)t * NPRE + r] = -1.0;
    } else {
      unsigned int idx = ~(unsigned int)(v & 0xFFFFFFFFull);
      int a = (int)(idx % 3u);
      int hw = (int)(idx / 3u);
      double d0 = (double)bbx[(a * 4 + 0) * HW + hw];
      double d1 = (double)bbx[(a * 4 + 1) * HW + hw];
      double d2 = (double)bbx[(a * 4 + 2) * HW + hw];
      double d3 = (double)bbx[(a * 4 + 3) * HW + hw];
      double a0 = (double)anc[(size_t)idx * 4 + 0];
      double a1 = (double)anc[(size_t)idx * 4 + 1];
      double a2 = (double)anc[(size_t)idx * 4 + 2];
      double a3 = (double)anc[(size_t)idx * 4 + 3];
      double dw = fmin(fmax(d2, -RCLIP), RCLIP);
      double dh = fmin(fmax(d3, -RCLIP), RCLIP);
      double pw = a2 - a0, ph = a3 - a1;
      double px = (a0 + a2) * 0.5, py = (a1 + a3) * 0.5;
      double gw = pw * exp(dw), gh = ph * exp(dh);
      double gx = px + pw * d0, gy = py + ph * d1;
      double x1 = fmin(fmax(gx - 0.5 * gw, 0.0), 1344.0);
      double y1 = fmin(fmax(gy - 0.5 * gh, 0.0), 800.0);
      double x2 = fmin(fmax(gx + 0.5 * gw, 0.0), 1344.0);
      double y2 = fmin(fmax(gy + 0.5 * gh, 0.0), 800.0);
      SB[0] = x1; SB[1] = y1; SB[2] = x2; SB[3] = y2;
      float f = unflipf_dev(key);
      p.selScores[(size_t)t * NPRE + r] = 1.0 / (1.0 + exp(-(double)f));
    }
  }
}

// --- 5. IoU -> suppression bitmask. 8 rows share each column load. ----------
__global__ __launch_bounds__(640) void k_iou(RPNParams p) {
  int bx = blockIdx.x;
  int t = bx / 25;
  int q = bx % 25;
  __shared__ float X1[2048], Y1[2048], X2[2048], Y2[2048], AR[2048];
  const double* SB = p.selBoxes + (size_t)t * NPRE * 4;
  for (int i = threadIdx.x; i < 2048; i += 640) {
    float x1 = 0.f, y1 = 0.f, x2 = 0.f, y2 = 0.f;
    if (i < NPRE) {
      x1 = (float)SB[i * 4 + 0]; y1 = (float)SB[i * 4 + 1];
      x2 = (float)SB[i * 4 + 2]; y2 = (float)SB[i * 4 + 3];
    }
    X1[i] = x1; Y1[i] = y1; X2[i] = x2; Y2[i] = y2;
    AR[i] = (x2 - x1) * (y2 - y1);
  }
  __syncthreads();
  int wave = threadIdx.x >> 6, lane = threadIdx.x & 63;
  int g = q + 25 * wave;  // [0,250)
  int i0 = g * 8;
  float x1i[8], y1i[8], x2i[8], y2i[8], ai[8];
#pragma unroll
  for (int r = 0; r < 8; r++) {
    int i = i0 + r;
    x1i[r] = X1[i]; y1i[r] = Y1[i]; x2i[r] = X2[i]; y2i[r] = Y2[i];
    ai[r] = AR[i];
  }
  int c0 = i0 >> 6;
  int j0 = c0 * 64 + lane;
  float cx1 = X1[j0], cy1 = Y1[j0], cx2 = X2[j0], cy2 = Y2[j0], car = AR[j0];
  for (int k = c0; k < 32; k++) {
    float nx1 = 0.f, ny1 = 0.f, nx2 = 0.f, ny2 = 0.f, nar = 0.f;
    if (k + 1 < 32) {  // prefetch next column word
      int jn = (k + 1) * 64 + lane;
      nx1 = X1[jn]; ny1 = Y1[jn]; nx2 = X2[jn]; ny2 = Y2[jn];
      nar = AR[jn];
    }
    int j = k * 64 + lane;
    bool jin = j < NPRE;
    bool pred[8], need[8];
    bool needAny = false;
#pragma unroll
    for (int r = 0; r < 8; r++) {
      int i = i0 + r;
      bool valid = jin && (j > i);
      float lx = fmaxf(x1i[r], cx1), ly = fmaxf(y1i[r], cy1);
      float rx = fminf(x2i[r], cx2), ry = fminf(y2i[r], cy2);
      float w = fmaxf(rx - lx, 0.0f), h = fmaxf(ry - ly, 0.0f);
      float inter = w * h;
      float uni = fmaxf(ai[r] + car - inter, 1e-6f);
      float diff = inter - 0.7f * uni;
      pred[r] = valid && (diff > 0.0f);
      need[r] = valid && (fabsf(diff) <= 4.0f + 1e-5f * uni);
      needAny |= need[r];
    }
    if (__any(needAny)) {  // rare: exact fp64 near the 0.7 boundary
#pragma unroll
      for (int r = 0; r < 8; r++) {
        if (need[r]) {
          int i = i0 + r;
          double a0 = SB[i * 4 + 0], b0 = SB[i * 4 + 1];
          double a2 = SB[i * 4 + 2], b2 = SB[i * 4 + 3];
          double c0d = SB[j * 4 + 0], d0 = SB[j * 4 + 1];
          double c2 = SB[j * 4 + 2], d2 = SB[j * 4 + 3];
          double dai = (a2 - a0) * (b2 - b0);
          double daj = (c2 - c0d) * (d2 - d0);
          double lxd = fmax(a0, c0d), lyd = fmax(b0, d0);
          double rxd = fmin(a2, c2), ryd = fmin(b2, d2);
          double wd = fmax(rxd - lxd, 0.0), hd = fmax(ryd - lyd, 0.0);
          double interd = wd * hd;
          double unid = fmax(dai + daj - interd, 1e-6);
          pred[r] = (interd / unid) > 0.7;
        }
      }
    }
#pragma unroll
    for (int r = 0; r < 8; r++) {
      unsigned long long word = __ballot(pred[r]);
      if (lane == 0) p.mask[((size_t)t * NPRE + i0 + r) * 32 + k] = word;
    }
    cx1 = nx1; cy1 = ny1; cx2 = nx2; cy2 = ny2; car = nar;
  }
}

// --- 6. greedy NMS (7 producers + 1 consumer) FUSED with re-rank ------------
#define GRP_N 63
#define RING 6
__global__ __launch_bounds__(512) void k_greedy(RPNParams p) {
  int t = blockIdx.x;
  int tid = threadIdx.x;
  __shared__ unsigned long long ring[RING * 1024];  // 48 KB
  __shared__ int ready[GRP_N];
  __shared__ int cons_s;
  __shared__ unsigned long long kw[32], aw[32], bw[32];
  __shared__ unsigned int prefA[33], prefB[33];
  volatile int* rdy = ready;
  volatile int* cons = &cons_s;
  const unsigned long long* MK = p.mask + (size_t)t * NPRE * 32;
  for (int i = tid; i < GRP_N; i += 512) ready[i] = 0;
  if (tid == 0) cons_s = 0;
  __syncthreads();

  int wave = tid >> 6, lane = tid & 63;
  if (wave >= 1) {
    // ---------------- producer waves (7) ----------------
    for (int g = wave - 1; g < GRP_N; g += 7) {
      while (g - *cons >= RING) __builtin_amdgcn_s_sleep(1);
      unsigned long long v[16];
#pragma unroll
      for (int k = 0; k < 16; k++) {
        int idx = k * 64 + lane;           // 0..1023
        int row = g * 32 + (idx >> 5);
        v[k] = (row < NPRE) ? MK[(size_t)row * 32 + (idx & 31)] : 0ull;
      }
      int slot = g % RING;
#pragma unroll
      for (int k = 0; k < 16; k++)
        ring[slot * 1024 + k * 64 + lane] = v[k];
      __threadfence_block();  // data visible before publish
      if (lane == 0) rdy[g] = 1;
    }
  } else {
    // ---------------- consumer wave ----------------
    unsigned long long supp = 0ull, keep = 0ull;  // lane j<32: word j
    for (int g = 0; g < GRP_N; g++) {
      while (rdy[g] == 0) { }  // busy-poll
      __threadfence_block();
      int slot = g % RING;
      int c = g >> 1;           // owner chunk (uniform scalar)
      int base = (g & 1) * 32;  // bit offset within the chunk word
      unsigned long long rv[32];
#pragma unroll
      for (int r = 0; r < 32; r++)
        rv[r] = ring[slot * 1024 + r * 32 + (lane & 31)];
      // broadcast supp[c]>>base (32-bit half) from lane c via readlane
      unsigned int sh = (unsigned int)(supp >> base);
      unsigned int s32 = (unsigned int)__builtin_amdgcn_readlane((int)sh, c);
      // branchless closure on ALL lanes (own rv; only lane c meaningful)
      unsigned int kg = 0;
#pragma unroll
      for (int r = 0; r < 32; r++) {
        unsigned int rvh = (unsigned int)(rv[r] >> base);
        bool kp = (s32 & (1u << r)) == 0u;
        kg |= kp ? (1u << r) : 0u;
        s32 |= kp ? rvh : 0u;
      }
      kg = (unsigned int)__builtin_amdgcn_readlane((int)kg, c);  // scalar
      // apply: OR kept rows' column words (kg is uniform scalar)
      unsigned long long acc0 = 0ull, acc1 = 0ull;
#pragma unroll
      for (int r = 0; r < 32; r += 2) {
        acc0 |= ((kg >> r) & 1u) ? rv[r] : 0ull;
        acc1 |= ((kg >> (r + 1)) & 1u) ? rv[r + 1] : 0ull;
      }
      supp |= acc0 | acc1;
      keep |= (lane == c) ? ((unsigned long long)kg << base) : 0ull;
      __threadfence_block();  // rv reads retired before freeing slot
      if (lane == 63) *cons = g + 1;
    }
    if (lane < 32) kw[lane] = keep;
  }
  __syncthreads();

  // ---------------- fused re-rank (all 8 waves) ----------------
  for (int ch = wave; ch < 32; ch += 8) {
    int i = ch * 64 + lane;
    bool inr = i < NPRE;
    bool kb = inr && ((kw[ch] >> lane) & 1ull);
    bool A = kb && (inr ? (p.selScores[(size_t)t * NPRE + i] > -0.5) : false);
    bool B = inr && !A;
    unsigned long long wa = __ballot(A);
    unsigned long long wb = __ballot(B);
    if (lane == 0) { aw[ch] = wa; bw[ch] = wb; }
  }
  __syncthreads();
  if (tid == 0) {
    unsigned int ca = 0, cb = 0;
    for (int w = 0; w < 32; w++) {
      prefA[w] = ca; ca += __popcll(aw[w]);
      prefB[w] = cb; cb += __popcll(bw[w]);
    }
    prefA[32] = ca; prefB[32] = cb;
  }
  __syncthreads();
  unsigned int KA = prefA[32];
  for (int i = tid; i < NPRE; i += 512) {
    int w = i >> 6, bpos = i & 63;
    unsigned long long below = (bpos == 0) ? 0ull : (~0ull >> (64 - bpos));
    bool kb = (kw[w] >> bpos) & 1ull;
    double s = p.selScores[(size_t)t * NPRE + i];
    bool A = kb && (s > -0.5);
    unsigned int slot;
    double outs;
    if (A) {
      slot = prefA[w] + (unsigned int)__popcll(aw[w] & below);
      outs = s;
    } else {
      slot = KA + prefB[w] + (unsigned int)__popcll(bw[w] & below);
      outs = -1.0;
    }
    if (slot < NPOST) {
      p.postScores[(size_t)t * NPOST + slot] = outs;
      const double* SB = p.selBoxes + ((size_t)t * NPRE + i) * 4;
      float* PB = p.postBoxes + ((size_t)t * NPOST + slot) * 4;
      PB[0] = (float)SB[0]; PB[1] = (float)SB[1];
      PB[2] = (float)SB[2]; PB[3] = (float)SB[3];
    }
  }
}

// --- 8a. final cross-level top-1000: k_rank-shaped counting-rank ------------
__global__ void k_finalA(RPNParams p) {
  int bx = blockIdx.x;
  int b = bx / 80;        // image 0..1
  int rem = bx % 80;
  int s = rem >> 2;       // j-slice 0..19
  int ec = rem & 3;       // e-chunk 0..3
  int j0 = s * 256;
  __shared__ unsigned long long kj[256];
  int tid = threadIdx.x;  // 256
  {
    int e = j0 + tid;
    unsigned long long v = 0ull;
    if (e < 5000) {
      int l = e / 1000, slot = e - l * 1000;
      int t = l * 2 + b;
      v = flip64_dev(p.postScores[(size_t)t * NPOST + slot]);
    }
    kj[tid] = v;
  }
  __syncthreads();
  int eidx[5];
  unsigned long long ke[5];
  unsigned int r[5];
#pragma unroll
  for (int k = 0; k < 5; k++) {
    int e = ec * 1280 + k * 256 + tid;
    eidx[k] = (e < 5000) ? e : -1;
    if (eidx[k] >= 0) {
      int l = e / 1000, slot = e - l * 1000;
      int t = l * 2 + b;
      ke[k] = flip64_dev(p.postScores[(size_t)t * NPOST + slot]);
    } else {
      ke[k] = 0ull;
    }
    r[k] = 0;
  }
  for (int j = 0; j < 256; j++) {
    unsigned long long vj = kj[j];
    int jg = j0 + j;
#pragma unroll
    for (int k = 0; k < 5; k++)
      r[k] += (vj > ke[k] || (vj == ke[k] && jg < eidx[k])) ? 1u : 0u;
  }
#pragma unroll
  for (int k = 0; k < 5; k++)
    if (eidx[k] >= 0)
      p.partial[((size_t)b * 20 + s) * 5000 + eidx[k]] = r[k];
}

// --- 8b. reduce ranks (20 slices), gather output boxes ----------------------
__global__ void k_finalB(RPNParams p) {
  int b = blockIdx.x / 5;
  int ch = blockIdx.x % 5;
  int tid = threadIdx.x;  // 1024
  if (tid < 1000) {
    int e = ch * 1000 + tid;
    unsigned int r = 0;
#pragma unroll
    for (int s = 0; s < 20; s++)
      r += p.partial[((size_t)b * 20 + s) * 5000 + e];
    if (r < NPOST) {
      int l = e / 1000, slot = e - l * 1000;
      int t = l * 2 + b;
      const float* PB = p.postBoxes + ((size_t)t * NPOST + slot) * 4;
      float* O = p.out + ((size_t)b * NPOST + r) * 4;
      O[0] = PB[0]; O[1] = PB[1]; O[2] = PB[2]; O[3] = PB[3];
    }
  }
}

extern "C" void kernel_launch(void* const* d_in, const int* in_sizes, int n_in,
                              void* d_out, int out_size, void* d_ws,
                              size_t ws_size, hipStream_t stream) {
  RPNParams p;
  bool interleaved = (n_in >= 2) && (in_sizes[1] == 4 * in_sizes[0]);
  for (int l = 0; l < 5; l++) {
    if (interleaved) {
      p.cls[l]  = (const float*)d_in[3 * l + 0];
      p.bbox[l] = (const float*)d_in[3 * l + 1];
      p.anc[l]  = (const float*)d_in[3 * l + 2];
    } else {
      p.cls[l]  = (const float*)d_in[l];
      p.bbox[l] = (const float*)d_in[5 + l];
      p.anc[l]  = (const float*)d_in[10 + l];
    }
  }
  char* w = (char*)d_ws;
  size_t off = 0;
  auto alloc = [&](size_t bytes) {
    off = (off + 255) & ~(size_t)255;
    void* r = w + off;
    off += bytes;
    return r;
  };
  p.mainCount = (unsigned int*)alloc(10 * 4);
  p.candCount = (unsigned int*)alloc(10 * 4);
  size_t zbytes = off;  // zeroed region: atomic counters only
  p.hist       = (unsigned int*)alloc((size_t)70 * 16384 * 4);
  p.histT      = (unsigned int*)alloc((size_t)8 * 16384 * 4);
  p.Bstar      = (unsigned int*)alloc(10 * 4);
  p.mainEK     = (unsigned long long*)alloc((size_t)10 * 2048 * 8);
  p.candEK     = (unsigned long long*)alloc((size_t)10 * 8192 * 8);
  p.ekG        = (unsigned long long*)alloc((size_t)10 * 2048 * 8);
  p.partialR   = (unsigned int*)alloc((size_t)10 * 8 * 2048 * 4);
  p.selBoxes   = (double*)alloc((size_t)10 * NPRE * 4 * 8);
  p.selScores  = (double*)alloc((size_t)10 * NPRE * 8);
  p.mask       = (unsigned long long*)alloc((size_t)10 * NPRE * 32 * 8);
  p.postScores = (double*)alloc((size_t)10 * NPOST * 8);
  p.postBoxes  = (float*)alloc((size_t)10 * NPOST * 4 * 4);
  p.partial    = (unsigned int*)alloc((size_t)2 * 20 * 5000 * 4);
  p.out = (float*)d_out;
  (void)ws_size; (void)out_size;

  hipMemsetAsync(d_ws, 0, zbytes, stream);
  k_hist<<<dim3(70), dim3(1024), 0, stream>>>(p);
  k_hred<<<dim3(128), dim3(1024), 0, stream>>>(p);
  k_find<<<dim3(8), dim3(1024), 0, stream>>>(p);
  k_compact<<<dim3(266), dim3(1024), 0, stream>>>(p);
  k_fill<<<dim3(10), dim3(256), 0, stream>>>(p);
  k_rank<<<dim3(80), dim3(256), 0, stream>>>(p);
  k_scatter<<<dim3(10), dim3(1024), 0, stream>>>(p);
  k_iou<<<dim3(250), dim3(640), 0, stream>>>(p);
  k_greedy<<<dim3(10), dim3(512), 0, stream>>>(p);
  k_finalA<<<dim3(160), dim3(256), 0, stream>>>(p);
  k_finalB<<<dim3(10), dim3(1024), 0, stream>>>(p);
}

// Round 16
// 388.116 us; speedup vs baseline: 1.2041x; 1.0038x over previous
//
#include <hip/hip_runtime.h>
#include <cmath>

// ---------------------------------------------------------------------------
// RPN head post-processing (mmdet GetBboxes-style), exact-semantics HIP port.
//
// Correctness: ordering-critical math fp64-exact (sigmoid, delta2bbox) or
// fp64-equivalent (IoU: fp32 filter + fp64 fallback band); top-k ordering on
// raw fp32 logit bits (monotone == fp64 sigmoid order; ties -> lower index).
//
// R15 PM: k_greedy at 72us = 2743cy/group -- 2x the issue-count model
// because the consumer wave SHARED its SIMD with a producer (8 waves/CU,
// round-robin issue halves a serial wave's rate). R16: 256 threads =
// 1 consumer + 3 producers, one wave per SIMD (consumer at full issue);
// group loop unrolled x2 so base is constant (kills 64-bit shifts);
// apply uses scalar-uniform branch on kg (SGPR) around one v_or_b64.
// ---------------------------------------------------------------------------

#define NPRE 2000
#define NPOST 1000

static __device__ __forceinline__ unsigned int flipf_dev(float f) {
  unsigned int u = __float_as_uint(f);
  return (u & 0x80000000u) ? ~u : (u | 0x80000000u);
}
static __device__ __forceinline__ float unflipf_dev(unsigned int k) {
  unsigned int u = (k & 0x80000000u) ? (k ^ 0x80000000u) : ~k;
  return __uint_as_float(u);
}
static __device__ __forceinline__ unsigned long long flip64_dev(double d) {
  unsigned long long u = (unsigned long long)__double_as_longlong(d);
  return (u & 0x8000000000000000ull) ? ~u : (u | 0x8000000000000000ull);
}

struct RPNParams {
  const float* cls[5];
  const float* bbox[5];
  const float* anc[5];
  unsigned int* hist;          // [70][16384] private per-block 14-bit hists
  unsigned int* histT;         // [8][16384] per-task reduced hists
  unsigned int* mainCount;     // [10]
  unsigned int* candCount;     // [10]
  unsigned int* Bstar;         // [10]
  unsigned long long* mainEK;  // [10][2048]  packed (key<<32)|~idx
  unsigned long long* candEK;  // [10][8192]
  unsigned long long* ekG;     // [10][2048]  assembled top-2000 (+pads)
  unsigned int* partialR;      // [10][8][2048] sliced ranks
  double* selBoxes;            // [10][2000][4]
  double* selScores;           // [10][2000]
  unsigned long long* mask;    // [10][2000][32]
  double* postScores;          // [10][1000]
  float* postBoxes;            // [10][1000][4]
  unsigned int* partial;       // [2][20][5000]
  float* out;                  // [2][1000][4]
};

__device__ __constant__ int c_NL[5]  = {201600, 50400, 12600, 3150, 819};
__device__ __constant__ int c_HW[5]  = {67200, 16800, 4200, 1050, 273};
// blocks-per-task at 2048 elements/block (levels 0..3 x 2 images) -- compact
__device__ __constant__ int c_BPT[8] = {99, 99, 25, 25, 7, 7, 2, 2};
// blocks-per-task at 8192 elements/block -- hist (total 70)
__device__ __constant__ int c_BPT12[8] = {25, 25, 7, 7, 2, 2, 1, 1};
__device__ __constant__ int c_HSTART[8] = {0, 25, 50, 57, 64, 66, 68, 69};

static __device__ __forceinline__ void map_block(int bx, int& t, int& chunk) {
  int start = 0;
  t = 0;
  for (int k = 0; k < 8; k++) {
    if (bx < start + c_BPT[k]) { t = k; break; }
    start += c_BPT[k];
  }
  chunk = bx - start;
}
static __device__ __forceinline__ void map_block12(int bx, int& t, int& chunk) {
  int start = 0;
  t = 0;
  for (int k = 0; k < 8; k++) {
    if (bx < start + c_BPT12[k]) { t = k; break; }
    start += c_BPT12[k];
  }
  chunk = bx - start;
}

// --- 1. per-block PRIVATE 14-bit histogram (LDS atomics, no global atomics) -
__global__ __launch_bounds__(1024) void k_hist(RPNParams p) {
  __shared__ unsigned int lh[16384];  // 64 KB
  int t, chunk;
  map_block12(blockIdx.x, t, chunk);
  int l = t >> 1, b = t & 1;
  int N = c_NL[l], HW = c_HW[l];
  const float* cls = p.cls[l] + (size_t)b * 3 * HW;
  int tid = threadIdx.x;
  for (int i = tid; i < 16384; i += 1024) lh[i] = 0;
  __syncthreads();
  int base = chunk * 8192 + tid;
#pragma unroll
  for (int k = 0; k < 8; k++) {
    int n = base + k * 1024;
    if (n < N) {
      int a = n % 3, hw = n / 3;
      unsigned int key = flipf_dev(cls[a * HW + hw]);
      atomicAdd(&lh[key >> 18], 1u);
    }
  }
  __syncthreads();
  unsigned int* hout = p.hist + (size_t)blockIdx.x * 16384;
  for (int i = tid; i < 16384; i += 1024) hout[i] = lh[i];
}

// --- 1b. reduce private hists -> per-task hist (128 blocks, 1 bin/thread) ---
__global__ __launch_bounds__(1024) void k_hred(RPNParams p) {
  int t = blockIdx.x >> 4;       // task 0..7
  int slice = blockIdx.x & 15;   // 0..15
  int bin = slice * 1024 + threadIdx.x;
  int start = c_HSTART[t];
  int bpt = c_BPT12[t];
  unsigned int s0 = 0, s1 = 0, s2 = 0, s3 = 0;
  int bb = 0;
  for (; bb + 4 <= bpt; bb += 4) {
    s0 += p.hist[(size_t)(start + bb + 0) * 16384 + bin];
    s1 += p.hist[(size_t)(start + bb + 1) * 16384 + bin];
    s2 += p.hist[(size_t)(start + bb + 2) * 16384 + bin];
    s3 += p.hist[(size_t)(start + bb + 3) * 16384 + bin];
  }
  for (; bb < bpt; bb++) s0 += p.hist[(size_t)(start + bb) * 16384 + bin];
  p.histT[(size_t)t * 16384 + bin] = s0 + s1 + s2 + s3;
}

// --- 2. find threshold bucket B* per task (reads reduced hist) --------------
__global__ __launch_bounds__(1024) void k_find(RPNParams p) {
  int t = blockIdx.x;  // 0..7
  __shared__ unsigned int H[16384];  // 64 KB
  __shared__ unsigned int S[1024];
  __shared__ int gsel;
  __shared__ unsigned int baseAbove;
  int tid = threadIdx.x;  // 1024
  const unsigned int* hT = p.histT + (size_t)t * 16384;
  for (int bin = tid; bin < 16384; bin += 1024) H[bin] = hT[bin];
  __syncthreads();
  {
    unsigned int s = 0;
#pragma unroll
    for (int k = 0; k < 16; k++) s += H[tid * 16 + k];
    S[tid] = s;
  }
  __syncthreads();
  for (int off = 1; off < 1024; off <<= 1) {
    unsigned int add = (tid + off < 1024) ? S[tid + off] : 0u;
    __syncthreads();
    S[tid] += add;
    __syncthreads();
  }
  const unsigned int need = NPRE;
  if (S[tid] >= need && (tid == 1023 || S[tid + 1] < need)) {
    gsel = tid;
    baseAbove = (tid == 1023) ? 0u : S[tid + 1];
  }
  __syncthreads();
  if (tid == 0) {
    int gg = gsel;
    unsigned int c = baseAbove;
    int bstar = gg * 16;
    for (int bb = 15; bb >= 0; bb--) {
      c += H[gg * 16 + bb];
      if (c >= need) { bstar = gg * 16 + bb; break; }
    }
    p.Bstar[t] = (unsigned int)bstar;
  }
}

// --- 3. compaction: above-bucket -> main, == bucket -> cand (14-bit) --------
__global__ void k_compact(RPNParams p) {
  int t, chunk;
  map_block(blockIdx.x, t, chunk);
  int l = t >> 1, b = t & 1;
  int N = c_NL[l], HW = c_HW[l];
  const float* cls = p.cls[l] + (size_t)b * 3 * HW;
  unsigned int Bs = p.Bstar[t];
  int base = chunk * 2048 + threadIdx.x;
  for (int k = 0; k < 2; k++) {
    int n = base + k * 1024;
    if (n < N) {
      int a = n % 3, hw = n / 3;
      unsigned int key = flipf_dev(cls[a * HW + hw]);
      unsigned int hi = key >> 18;
      unsigned long long ek =
          ((unsigned long long)key << 32) | (unsigned int)(~(unsigned int)n);
      if (hi > Bs) {
        unsigned int pos = atomicAdd(&p.mainCount[t], 1u);
        if (pos < 2048u) p.mainEK[(size_t)t * 2048 + pos] = ek;
      } else if (hi == Bs) {
        unsigned int pos = atomicAdd(&p.candCount[t], 1u);
        if (pos < 8192u) p.candEK[(size_t)t * 8192 + pos] = ek;
      }
    }
  }
}

// --- 4a. fill ekG[t][2048]: exact top-2000 keys + pads ----------------------
__global__ void k_fill(RPNParams p) {
  int t = blockIdx.x;  // 0..9
  int l = t >> 1, b = t & 1;
  int N = c_NL[l], HW = c_HW[l];
  int tid = threadIdx.x;  // 256
  unsigned long long* ekG = p.ekG + (size_t)t * 2048;
  if (N >= NPRE) {
    unsigned int cGT = min(p.mainCount[t], 2000u);
    unsigned int nC = min(p.candCount[t], 8192u);
    unsigned int needIn = 2000u - cGT;
    for (unsigned int m = tid; m < cGT; m += 256)
      ekG[m] = p.mainEK[(size_t)t * 2048 + m];
    const unsigned long long* cek = p.candEK + (size_t)t * 8192;
    for (unsigned int e = tid; e < nC; e += 256) {
      unsigned long long ve = cek[e];
      unsigned int r = 0;
      for (unsigned int j = 0; j < nC; j++) r += (cek[j] > ve) ? 1u : 0u;
      if (r < needIn) ekG[cGT + r] = ve;
    }
    for (unsigned int r2 = 2000u + tid; r2 < 2048u; r2 += 256)
      ekG[r2] = (unsigned long long)(unsigned int)(~r2);
  } else {
    // level 4 (N=819): pad path -- key 0 pads below all finite logits
    const float* cls = p.cls[l] + (size_t)b * 3 * HW;
    for (int r = tid; r < 2048; r += 256) {
      if (r < N) {
        int a = r % 3, hw = r / 3;
        unsigned int key = flipf_dev(cls[a * HW + hw]);
        ekG[r] = ((unsigned long long)key << 32) |
                 (unsigned int)(~(unsigned int)r);
      } else {
        ekG[r] = (unsigned long long)(unsigned int)(~(unsigned int)r);
      }
    }
  }
}

// --- 4b. sliced counting-rank: 8 slices x 10 tasks --------------------------
__global__ void k_rank(RPNParams p) {
  int t = blockIdx.x >> 3;
  int s = blockIdx.x & 7;
  int tid = threadIdx.x;  // 256
  __shared__ unsigned long long sl[256];
  const unsigned long long* ekG = p.ekG + (size_t)t * 2048;
  sl[tid] = ekG[s * 256 + tid];
  __syncthreads();
  unsigned long long ve[8];
  unsigned int r[8];
#pragma unroll
  for (int k = 0; k < 8; k++) {
    ve[k] = ekG[k * 256 + tid];
    r[k] = 0;
  }
  for (int j = 0; j < 256; j++) {
    unsigned long long vj = sl[j];
#pragma unroll
    for (int k = 0; k < 8; k++) r[k] += (vj > ve[k]) ? 1u : 0u;
  }
  unsigned int* out = p.partialR + ((size_t)t * 8 + s) * 2048;
#pragma unroll
  for (int k = 0; k < 8; k++) out[k * 256 + tid] = r[k];
}

// --- 4c. scatter by total rank + fp64 decode --------------------------------
__global__ void k_scatter(RPNParams p) {
  int t = blockIdx.x;  // 0..9
  int l = t >> 1, b = t & 1;
  int HW = c_HW[l];
  int tid = threadIdx.x;  // 1024
  __shared__ unsigned long long srt[2048];
  const unsigned long long* ekG = p.ekG + (size_t)t * 2048;
  for (int e = tid; e < 2048; e += 1024) {
    unsigned int rk = 0;
#pragma unroll
    for (int s = 0; s < 8; s++)
      rk += p.partialR[((size_t)t * 8 + s) * 2048 + e];
    srt[rk] = ekG[e];
  }
  __syncthreads();

  const double RCLIP = fabs(log(16.0 / 1000.0));  // mmdet wh_ratio_clip
  const float* bbx = p.bbox[l] + (size_t)b * 12 * HW;
  const float* anc = p.anc[l];
  for (int r = tid; r < NPRE; r += 1024) {
    unsigned long long v = srt[r];
    unsigned int key = (unsigned int)(v >> 32);
    double* SB = p.selBoxes + ((size_t)t * NPRE + r) * 4;
    if (key == 0u) {  // pad: zero anchors/deltas -> zero box, score -1
      SB[0] = 0.0; SB[1] = 0.0; SB[2] = 0.0; SB[3] = 0.0;
      p.selScores[(size_t)t * NPRE + r] = -1.0;
    } else {
      unsigned int idx = ~(unsigned int)(v & 0xFFFFFFFFull);
      int a = (int)(idx % 3u);
      int hw = (int)(idx / 3u);
      double d0 = (double)bbx[(a * 4 + 0) * HW + hw];
      double d1 = (double)bbx[(a * 4 + 1) * HW + hw];
      double d2 = (double)bbx[(a * 4 + 2) * HW + hw];
      double d3 = (double)bbx[(a * 4 + 3) * HW + hw];
      double a0 = (double)anc[(size_t)idx * 4 + 0];
      double a1 = (double)anc[(size_t)idx * 4 + 1];
      double a2 = (double)anc[(size_t)idx * 4 + 2];
      double a3 = (double)anc[(size_t)idx * 4 + 3];
      double dw = fmin(fmax(d2, -RCLIP), RCLIP);
      double dh = fmin(fmax(d3, -RCLIP), RCLIP);
      double pw = a2 - a0, ph = a3 - a1;
      double px = (a0 + a2) * 0.5, py = (a1 + a3) * 0.5;
      double gw = pw * exp(dw), gh = ph * exp(dh);
      double gx = px + pw * d0, gy = py + ph * d1;
      double x1 = fmin(fmax(gx - 0.5 * gw, 0.0), 1344.0);
      double y1 = fmin(fmax(gy - 0.5 * gh, 0.0), 800.0);
      double x2 = fmin(fmax(gx + 0.5 * gw, 0.0), 1344.0);
      double y2 = fmin(fmax(gy + 0.5 * gh, 0.0), 800.0);
      SB[0] = x1; SB[1] = y1; SB[2] = x2; SB[3] = y2;
      float f = unflipf_dev(key);
      p.selScores[(size_t)t * NPRE + r] = 1.0 / (1.0 + exp(-(double)f));
    }
  }
}

// --- 5. IoU -> suppression bitmask. 8 rows share each column load. ----------
__global__ __launch_bounds__(640) void k_iou(RPNParams p) {
  int bx = blockIdx.x;
  int t = bx / 25;
  int q = bx % 25;
  __shared__ float X1[2048], Y1[2048], X2[2048], Y2[2048], AR[2048];
  const double* SB = p.selBoxes + (size_t)t * NPRE * 4;
  for (int i = threadIdx.x; i < 2048; i += 640) {
    float x1 = 0.f, y1 = 0.f, x2 = 0.f, y2 = 0.f;
    if (i < NPRE) {
      x1 = (float)SB[i * 4 + 0]; y1 = (float)SB[i * 4 + 1];
      x2 = (float)SB[i * 4 + 2]; y2 = (float)SB[i * 4 + 3];
    }
    X1[i] = x1; Y1[i] = y1; X2[i] = x2; Y2[i] = y2;
    AR[i] = (x2 - x1) * (y2 - y1);
  }
  __syncthreads();
  int wave = threadIdx.x >> 6, lane = threadIdx.x & 63;
  int g = q + 25 * wave;  // [0,250)
  int i0 = g * 8;
  float x1i[8], y1i[8], x2i[8], y2i[8], ai[8];
#pragma unroll
  for (int r = 0; r < 8; r++) {
    int i = i0 + r;
    x1i[r] = X1[i]; y1i[r] = Y1[i]; x2i[r] = X2[i]; y2i[r] = Y2[i];
    ai[r] = AR[i];
  }
  int c0 = i0 >> 6;
  int j0 = c0 * 64 + lane;
  float cx1 = X1[j0], cy1 = Y1[j0], cx2 = X2[j0], cy2 = Y2[j0], car = AR[j0];
  for (int k = c0; k < 32; k++) {
    float nx1 = 0.f, ny1 = 0.f, nx2 = 0.f, ny2 = 0.f, nar = 0.f;
    if (k + 1 < 32) {  // prefetch next column word
      int jn = (k + 1) * 64 + lane;
      nx1 = X1[jn]; ny1 = Y1[jn]; nx2 = X2[jn]; ny2 = Y2[jn];
      nar = AR[jn];
    }
    int j = k * 64 + lane;
    bool jin = j < NPRE;
    bool pred[8], need[8];
    bool needAny = false;
#pragma unroll
    for (int r = 0; r < 8; r++) {
      int i = i0 + r;
      bool valid = jin && (j > i);
      float lx = fmaxf(x1i[r], cx1), ly = fmaxf(y1i[r], cy1);
      float rx = fminf(x2i[r], cx2), ry = fminf(y2i[r], cy2);
      float w = fmaxf(rx - lx, 0.0f), h = fmaxf(ry - ly, 0.0f);
      float inter = w * h;
      float uni = fmaxf(ai[r] + car - inter, 1e-6f);
      float diff = inter - 0.7f * uni;
      pred[r] = valid && (diff > 0.0f);
      need[r] = valid && (fabsf(diff) <= 4.0f + 1e-5f * uni);
      needAny |= need[r];
    }
    if (__any(needAny)) {  // rare: exact fp64 near the 0.7 boundary
#pragma unroll
      for (int r = 0; r < 8; r++) {
        if (need[r]) {
          int i = i0 + r;
          double a0 = SB[i * 4 + 0], b0 = SB[i * 4 + 1];
          double a2 = SB[i * 4 + 2], b2 = SB[i * 4 + 3];
          double c0d = SB[j * 4 + 0], d0 = SB[j * 4 + 1];
          double c2 = SB[j * 4 + 2], d2 = SB[j * 4 + 3];
          double dai = (a2 - a0) * (b2 - b0);
          double daj = (c2 - c0d) * (d2 - d0);
          double lxd = fmax(a0, c0d), lyd = fmax(b0, d0);
          double rxd = fmin(a2, c2), ryd = fmin(b2, d2);
          double wd = fmax(rxd - lxd, 0.0), hd = fmax(ryd - lyd, 0.0);
          double interd = wd * hd;
          double unid = fmax(dai + daj - interd, 1e-6);
          pred[r] = (interd / unid) > 0.7;
        }
      }
    }
#pragma unroll
    for (int r = 0; r < 8; r++) {
      unsigned long long word = __ballot(pred[r]);
      if (lane == 0) p.mask[((size_t)t * NPRE + i0 + r) * 32 + k] = word;
    }
    cx1 = nx1; cy1 = ny1; cx2 = nx2; cy2 = ny2; car = nar;
  }
}

// --- 6. greedy NMS: 1 consumer + 3 producer waves (one per SIMD) ------------
// 32-row groups; base constant via x2 group-loop unroll; apply uses
// scalar-uniform branch on kg (SGPR after readlane).
#define GRP_N 63
#define RING 6
__global__ __launch_bounds__(256) void k_greedy(RPNParams p) {
  int t = blockIdx.x;
  int tid = threadIdx.x;
  __shared__ unsigned long long ring[RING * 1024];  // 48 KB
  __shared__ int ready[GRP_N];
  __shared__ int cons_s;
  __shared__ unsigned long long kw[32], aw[32], bw[32];
  __shared__ unsigned int prefA[33], prefB[33];
  volatile int* rdy = ready;
  volatile int* cons = &cons_s;
  const unsigned long long* MK = p.mask + (size_t)t * NPRE * 32;
  for (int i = tid; i < GRP_N; i += 256) ready[i] = 0;
  if (tid == 0) cons_s = 0;
  __syncthreads();

  int wave = tid >> 6, lane = tid & 63;
  if (wave >= 1) {
    // ---------------- producer waves (3, each alone on a SIMD) -------------
    for (int g = wave - 1; g < GRP_N; g += 3) {
      while (g - *cons >= RING) __builtin_amdgcn_s_sleep(1);
      unsigned long long v[16];
#pragma unroll
      for (int k = 0; k < 16; k++) {
        int idx = k * 64 + lane;           // 0..1023
        int row = g * 32 + (idx >> 5);
        v[k] = (row < NPRE) ? MK[(size_t)row * 32 + (idx & 31)] : 0ull;
      }
      int slot = g % RING;
#pragma unroll
      for (int k = 0; k < 16; k++)
        ring[slot * 1024 + k * 64 + lane] = v[k];
      __threadfence_block();  // data visible before publish
      if (lane == 0) rdy[g] = 1;
    }
  } else {
    // ---------------- consumer wave (alone on its SIMD) --------------------
    unsigned long long supp = 0ull, keep = 0ull;  // lane j<32: word j
    auto doGroup = [&](int g, int base) {
      while (rdy[g] == 0) { }  // busy-poll
      __threadfence_block();
      int slot = g % RING;
      int c = g >> 1;  // owner chunk (uniform scalar)
      unsigned long long rv[32];
#pragma unroll
      for (int r = 0; r < 32; r++)
        rv[r] = ring[slot * 1024 + r * 32 + (lane & 31)];
      unsigned int sh = (unsigned int)(supp >> base);  // base is literal
      unsigned int s32 = (unsigned int)__builtin_amdgcn_readlane((int)sh, c);
      unsigned int kg = 0;
#pragma unroll
      for (int r = 0; r < 32; r++) {
        unsigned int rvh = (unsigned int)(rv[r] >> base);  // reg-select
        bool kp = (s32 & (1u << r)) == 0u;
        kg |= kp ? (1u << r) : 0u;
        s32 |= kp ? rvh : 0u;
      }
      kg = (unsigned int)__builtin_amdgcn_readlane((int)kg, c);  // SGPR
      // apply: scalar-uniform branch per kept row -> single v_or_b64
#pragma unroll
      for (int r = 0; r < 32; r++) {
        if (kg & (1u << r)) supp |= rv[r];
      }
      keep |= (lane == c) ? ((unsigned long long)kg << base) : 0ull;
      __threadfence_block();  // rv reads retired before freeing slot
      if (lane == 63) *cons = g + 1;
    };
    for (int g = 0; g + 1 < GRP_N; g += 2) {
      doGroup(g, 0);
      doGroup(g + 1, 32);
    }
    doGroup(GRP_N - 1, 0);  // group 62 (even -> base 0)
    if (lane < 32) kw[lane] = keep;
  }
  __syncthreads();

  // ---------------- fused re-rank (all 4 waves) ----------------
  for (int ch = wave; ch < 32; ch += 4) {
    int i = ch * 64 + lane;
    bool inr = i < NPRE;
    bool kb = inr && ((kw[ch] >> lane) & 1ull);
    bool A = kb && (inr ? (p.selScores[(size_t)t * NPRE + i] > -0.5) : false);
    bool B = inr && !A;
    unsigned long long wa = __ballot(A);
    unsigned long long wb = __ballot(B);
    if (lane == 0) { aw[ch] = wa; bw[ch] = wb; }
  }
  __syncthreads();
  if (tid == 0) {
    unsigned int ca = 0, cb = 0;
    for (int w = 0; w < 32; w++) {
      prefA[w] = ca; ca += __popcll(aw[w]);
      prefB[w] = cb; cb += __popcll(bw[w]);
    }
    prefA[32] = ca; prefB[32] = cb;
  }
  __syncthreads();
  unsigned int KA = prefA[32];
  for (int i = tid; i < NPRE; i += 256) {
    int w = i >> 6, bpos = i & 63;
    unsigned long long below = (bpos == 0) ? 0ull : (~0ull >> (64 - bpos));
    bool kb = (kw[w] >> bpos) & 1ull;
    double s = p.selScores[(size_t)t * NPRE + i];
    bool A = kb && (s > -0.5);
    unsigned int slot;
    double outs;
    if (A) {
      slot = prefA[w] + (unsigned int)__popcll(aw[w] & below);
      outs = s;
    } else {
      slot = KA + prefB[w] + (unsigned int)__popcll(bw[w] & below);
      outs = -1.0;
    }
    if (slot < NPOST) {
      p.postScores[(size_t)t * NPOST + slot] = outs;
      const double* SB = p.selBoxes + ((size_t)t * NPRE + i) * 4;
      float* PB = p.postBoxes + ((size_t)t * NPOST + slot) * 4;
      PB[0] = (float)SB[0]; PB[1] = (float)SB[1];
      PB[2] = (float)SB[2]; PB[3] = (float)SB[3];
    }
  }
}

// --- 8a. final cross-level top-1000: k_rank-shaped counting-rank ------------
__global__ void k_finalA(RPNParams p) {
  int bx = blockIdx.x;
  int b = bx / 80;        // image 0..1
  int rem = bx % 80;
  int s = rem >> 2;       // j-slice 0..19
  int ec = rem & 3;       // e-chunk 0..3
  int j0 = s * 256;
  __shared__ unsigned long long kj[256];
  int tid = threadIdx.x;  // 256
  {
    int e = j0 + tid;
    unsigned long long v = 0ull;
    if (e < 5000) {
      int l = e / 1000, slot = e - l * 1000;
      int t = l * 2 + b;
      v = flip64_dev(p.postScores[(size_t)t * NPOST + slot]);
    }
    kj[tid] = v;
  }
  __syncthreads();
  int eidx[5];
  unsigned long long ke[5];
  unsigned int r[5];
#pragma unroll
  for (int k = 0; k < 5; k++) {
    int e = ec * 1280 + k * 256 + tid;
    eidx[k] = (e < 5000) ? e : -1;
    if (eidx[k] >= 0) {
      int l = e / 1000, slot = e - l * 1000;
      int t = l * 2 + b;
      ke[k] = flip64_dev(p.postScores[(size_t)t * NPOST + slot]);
    } else {
      ke[k] = 0ull;
    }
    r[k] = 0;
  }
  for (int j = 0; j < 256; j++) {
    unsigned long long vj = kj[j];
    int jg = j0 + j;
#pragma unroll
    for (int k = 0; k < 5; k++)
      r[k] += (vj > ke[k] || (vj == ke[k] && jg < eidx[k])) ? 1u : 0u;
  }
#pragma unroll
  for (int k = 0; k < 5; k++)
    if (eidx[k] >= 0)
      p.partial[((size_t)b * 20 + s) * 5000 + eidx[k]] = r[k];
}

// --- 8b. reduce ranks (20 slices), gather output boxes ----------------------
__global__ void k_finalB(RPNParams p) {
  int b = blockIdx.x / 5;
  int ch = blockIdx.x % 5;
  int tid = threadIdx.x;  // 1024
  if (tid < 1000) {
    int e = ch * 1000 + tid;
    unsigned int r = 0;
#pragma unroll
    for (int s = 0; s < 20; s++)
      r += p.partial[((size_t)b * 20 + s) * 5000 + e];
    if (r < NPOST) {
      int l = e / 1000, slot = e - l * 1000;
      int t = l * 2 + b;
      const float* PB = p.postBoxes + ((size_t)t * NPOST + slot) * 4;
      float* O = p.out + ((size_t)b * NPOST + r) * 4;
      O[0] = PB[0]; O[1] = PB[1]; O[2] = PB[2]; O[3] = PB[3];
    }
  }
}

extern "C" void kernel_launch(void* const* d_in, const int* in_sizes, int n_in,
                              void* d_out, int out_size, void* d_ws,
                              size_t ws_size, hipStream_t stream) {
  RPNParams p;
  bool interleaved = (n_in >= 2) && (in_sizes[1] == 4 * in_sizes[0]);
  for (int l = 0; l < 5; l++) {
    if (interleaved) {
      p.cls[l]  = (const float*)d_in[3 * l + 0];
      p.bbox[l] = (const float*)d_in[3 * l + 1];
      p.anc[l]  = (const float*)d_in[3 * l + 2];
    } else {
      p.cls[l]  = (const float*)d_in[l];
      p.bbox[l] = (const float*)d_in[5 + l];
      p.anc[l]  = (const float*)d_in[10 + l];
    }
  }
  char* w = (char*)d_ws;
  size_t off = 0;
  auto alloc = [&](size_t bytes) {
    off = (off + 255) & ~(size_t)255;
    void* r = w + off;
    off += bytes;
    return r;
  };
  p.mainCount = (unsigned int*)alloc(10 * 4);
  p.candCount = (unsigned int*)alloc(10 * 4);
  size_t zbytes = off;  // zeroed region: atomic counters only
  p.hist       = (unsigned int*)alloc((size_t)70 * 16384 * 4);
  p.histT      = (unsigned int*)alloc((size_t)8 * 16384 * 4);
  p.Bstar      = (unsigned int*)alloc(10 * 4);
  p.mainEK     = (unsigned long long*)alloc((size_t)10 * 2048 * 8);
  p.candEK     = (unsigned long long*)alloc((size_t)10 * 8192 * 8);
  p.ekG        = (unsigned long long*)alloc((size_t)10 * 2048 * 8);
  p.partialR   = (unsigned int*)alloc((size_t)10 * 8 * 2048 * 4);
  p.selBoxes   = (double*)alloc((size_t)10 * NPRE * 4 * 8);
  p.selScores  = (double*)alloc((size_t)10 * NPRE * 8);
  p.mask       = (unsigned long long*)alloc((size_t)10 * NPRE * 32 * 8);
  p.postScores = (double*)alloc((size_t)10 * NPOST * 8);
  p.postBoxes  = (float*)alloc((size_t)10 * NPOST * 4 * 4);
  p.partial    = (unsigned int*)alloc((size_t)2 * 20 * 5000 * 4);
  p.out = (float*)d_out;
  (void)ws_size; (void)out_size;

  hipMemsetAsync(d_ws, 0, zbytes, stream);
  k_hist<<<dim3(70), dim3(1024), 0, stream>>>(p);
  k_hred<<<dim3(128), dim3(1024), 0, stream>>>(p);
  k_find<<<dim3(8), dim3(1024), 0, stream>>>(p);
  k_compact<<<dim3(266), dim3(1024), 0, stream>>>(p);
  k_fill<<<dim3(10), dim3(256), 0, stream>>>(p);
  k_rank<<<dim3(80), dim3(256), 0, stream>>>(p);
  k_scatter<<<dim3(10), dim3(1024), 0, stream>>>(p);
  k_iou<<<dim3(250), dim3(640), 0, stream>>>(p);
  k_greedy<<<dim3(10), dim3(256), 0, stream>>>(p);
  k_finalA<<<dim3(160), dim3(256), 0, stream>>>(p);
  k_finalB<<<dim3(10), dim3(1024), 0, stream>>>(p);
}